// Round 14
// baseline (589.889 us; speedup 1.0000x reference)
//
#include <hip/hip_runtime.h>
#include <stdint.h>

#define B_   32
#define N_   4096
#define D_   256
#define H_   8
#define S_   16
#define DI_  512
#define HID_ 1024
#define CH_  8
#define NCHUNK_ 512
#define SCALE_ 0.0625f

typedef short  short8 __attribute__((ext_vector_type(8)));
typedef float  f32x4  __attribute__((ext_vector_type(4)));

__device__ __forceinline__ unsigned short f2bf(float x){
  union { float f; unsigned u; } v; v.f = x;
  unsigned r = v.u + 0x7FFFu + ((v.u >> 16) & 1u);
  return (unsigned short)(r >> 16);
}
__device__ __forceinline__ float bf2f(unsigned short u){
  union { unsigned u; float f; } v; v.u = ((unsigned)u) << 16; return v.f;
}

__device__ __forceinline__ void gld16(const void* g, void* l){
  __builtin_amdgcn_global_load_lds(
      (const __attribute__((address_space(1))) unsigned int*)g,
      (__attribute__((address_space(3))) unsigned int*)l, 16, 0, 0);
}

// ---------------- ws too small sentinel ----------------
__global__ void k_badws(float* out){ out[blockIdx.x*256 + threadIdx.x] = 1e9f; }

// ---------------- slots init ----------------
__global__ __launch_bounds__(256) void k_init_slots(
    const float* __restrict__ noise, const float* __restrict__ mu,
    const float* __restrict__ lsig, float* __restrict__ slots)
{
  int i = blockIdx.x*256 + threadIdx.x;   // < 131072
  int d = i & 255;
  slots[i] = mu[d] + expf(lsig[d]) * noise[i];
}

// ---------------- all 7 weight transposes in ONE launch ----------------
__global__ __launch_bounds__(256) void k_tr_all(
    const float* __restrict__ Wq,  const float* __restrict__ Wv,  const float* __restrict__ Wc,
    const float* __restrict__ wih, const float* __restrict__ whh,
    const float* __restrict__ W1,  const float* __restrict__ W2,
    float* __restrict__ WqT, float* __restrict__ WvT, float* __restrict__ WcT,
    float* __restrict__ wihT, float* __restrict__ whhT,
    float* __restrict__ W1T, float* __restrict__ W2T)
{
  __shared__ float t[32][33];
  const int id = blockIdx.x;
  const float* src; float* dst; int R, C, bx, by;
  if      (id < 128) { src=Wq;  dst=WqT;  R=512;  C=256;  int s=id;      bx=s&7;  by=s>>3; }
  else if (id < 256) { src=Wv;  dst=WvT;  R=512;  C=256;  int s=id-128;  bx=s&7;  by=s>>3; }
  else if (id < 384) { src=Wc;  dst=WcT;  R=256;  C=512;  int s=id-256;  bx=s&15; by=s>>4; }
  else if (id < 576) { src=wih; dst=wihT; R=768;  C=256;  int s=id-384;  bx=s&7;  by=s>>3; }
  else if (id < 768) { src=whh; dst=whhT; R=768;  C=256;  int s=id-576;  bx=s&7;  by=s>>3; }
  else if (id < 1024){ src=W1;  dst=W1T;  R=1024; C=256;  int s=id-768;  bx=s&7;  by=s>>3; }
  else               { src=W2;  dst=W2T;  R=256;  C=1024; int s=id-1024; bx=s&31; by=s>>5; }
  int c0 = bx*32, r0 = by*32;
  int tx = threadIdx.x, ty = threadIdx.y;   // 32 x 8
  for (int j = 0; j < 32; j += 8){
    int r = r0 + ty + j, c = c0 + tx;
    if (r < R && c < C) t[ty+j][tx] = src[(size_t)r*C + c];
  }
  __syncthreads();
  for (int j = 0; j < 32; j += 8){
    int c = c0 + ty + j, r = r0 + tx;
    if (c < C && r < R) dst[(size_t)c*R + r] = t[tx][ty+j];
  }
}

// ---------------- LN(x) -> xn bf16 [B][N][D] and xnT bf16 [B][D][N]  (exact R12, proven 77 us) ----------------
__global__ __launch_bounds__(256) void k_ln_x(
    const float* __restrict__ x, const float* __restrict__ g, const float* __restrict__ bb,
    unsigned short* __restrict__ xn, unsigned short* __restrict__ xnT)
{
  __shared__ __align__(16) char tile[32768];   // 64 rows x 256 bf16, swizzled
  const int blk = blockIdx.x;
  const int b  = blk >> 6;
  const int n0 = (blk & 63) * 64;
  const int t = threadIdx.x;
  const int lane = t & 63;
  const int w = t >> 6;
  float4 gv = *(const float4*)&g[lane*4];
  float4 bv = *(const float4*)&bb[lane*4];
#pragma unroll 1
  for (int it = 0; it < 16; ++it){
    const int nl = w*16 + it;
    const size_t row = (size_t)b*N_ + n0 + nl;
    float4 xv = *(const float4*)&x[row*256 + lane*4];
    float s = xv.x + xv.y + xv.z + xv.w;
    float q = xv.x*xv.x + xv.y*xv.y + xv.z*xv.z + xv.w*xv.w;
#pragma unroll
    for (int m = 1; m < 64; m <<= 1){ s += __shfl_xor(s, m); q += __shfl_xor(q, m); }
    float mean = s * 0.00390625f;
    float var  = q * 0.00390625f - mean*mean;
    float rs = rsqrtf(var + 1e-5f);
    unsigned short u0 = f2bf((xv.x-mean)*rs*gv.x + bv.x);
    unsigned short u1 = f2bf((xv.y-mean)*rs*gv.y + bv.y);
    unsigned short u2 = f2bf((xv.z-mean)*rs*gv.z + bv.z);
    unsigned short u3 = f2bf((xv.w-mean)*rs*gv.w + bv.w);
    uint2 pk; pk.x = (unsigned)u0 | ((unsigned)u1 << 16); pk.y = (unsigned)u2 | ((unsigned)u3 << 16);
    *(uint2*)&xn[row*256 + lane*4] = pk;
    *(uint2*)(tile + nl*512 + ((lane*8) ^ ((nl & 7) << 4))) = pk;
  }
  __syncthreads();
#pragma unroll 1
  for (int j = 0; j < 32; ++j){
    int flat = j*256 + t;           // 8192 dwords
    int d  = flat >> 5;             // 0..255
    int np = (flat & 31) * 2;       // n pair base
    unsigned short lo = *(const unsigned short*)(tile + np*512     + ((2*d) ^ ((np     & 7) << 4)));
    unsigned short hi = *(const unsigned short*)(tile + (np+1)*512 + ((2*d) ^ (((np+1) & 7) << 4)));
    *(unsigned*)&xnT[((size_t)b*D_ + d)*N_ + n0 + np] = (unsigned)lo | ((unsigned)hi << 16);
  }
}

// ---------------- pre2: fused LN(slots) + ql slice + qb + qp, one block per (b,h) ----------------
__global__ __launch_bounds__(256) void k_pre2(
    const float* __restrict__ slots, const float* __restrict__ lsg, const float* __restrict__ lsb,
    const float* __restrict__ WqT, const float* __restrict__ bq,
    const float* __restrict__ Wk, const float* __restrict__ bk,
    unsigned short* __restrict__ qp, float* __restrict__ qb)
{
  __shared__ float sn[16][256];     // LN(slots) rows for this b (16 KB)
  __shared__ float qls[16][64];     // ql slice for this h (4 KB)
  const int id = blockIdx.x;        // 256 = b*8 + h
  const int b = id >> 3, h = id & 7;
  const int t = threadIdx.x, lane = t & 63, w = t >> 6;
  {
    float4 gv = *(const float4*)&lsg[lane*4];
    float4 bvv = *(const float4*)&lsb[lane*4];
#pragma unroll
    for (int rr = 0; rr < 4; ++rr){
      int r = w*4 + rr;
      float4 v = *(const float4*)&slots[((size_t)(b*S_ + r))*D_ + lane*4];
      float s = v.x + v.y + v.z + v.w;
      float q = v.x*v.x + v.y*v.y + v.z*v.z + v.w*v.w;
#pragma unroll
      for (int m = 1; m < 64; m <<= 1){ s += __shfl_xor(s, m); q += __shfl_xor(q, m); }
      float mean = s * 0.00390625f;
      float var  = q * 0.00390625f - mean*mean;
      float rs = rsqrtf(var + 1e-5f);
      sn[r][lane*4+0] = (v.x-mean)*rs*gv.x + bvv.x;
      sn[r][lane*4+1] = (v.y-mean)*rs*gv.y + bvv.y;
      sn[r][lane*4+2] = (v.z-mean)*rs*gv.z + bvv.z;
      sn[r][lane*4+3] = (v.w-mean)*rs*gv.w + bvv.w;
    }
  }
  __syncthreads();
  // ql slice: rows w*4..+3, col h*64+lane, K=256
  {
    float acc[4] = {};
    const float* Wp = WqT + h*64 + lane;
#pragma unroll 4
    for (int k = 0; k < 256; ++k){
      float wv = Wp[(size_t)k*512];
      acc[0] += sn[w*4+0][k] * wv;
      acc[1] += sn[w*4+1][k] * wv;
      acc[2] += sn[w*4+2][k] * wv;
      acc[3] += sn[w*4+3][k] * wv;
    }
    float bqv = bq[h*64 + lane];
#pragma unroll
    for (int rr = 0; rr < 4; ++rr) qls[w*4+rr][lane] = acc[rr] + bqv;
  }
  __syncthreads();
  // qb: per row dot with bk_h
  {
    float bkv = bk[h*64 + lane];
#pragma unroll
    for (int rr = 0; rr < 4; ++rr){
      int r = w*4 + rr;
      float v = qls[r][lane] * bkv;
#pragma unroll
      for (int m = 1; m < 64; m <<= 1) v += __shfl_xor(v, m);
      if (lane == 0) qb[((size_t)b*H_ + h)*S_ + r] = v * SCALE_;
    }
  }
  // qp: rows w*4..+3, cols cc*64+lane, K=64
  {
    float acc[4][4] = {};   // [cc][rr]
    const float* Wp = Wk + (size_t)(h*64)*256 + lane;
#pragma unroll 2
    for (int k = 0; k < 64; ++k){
      float q0 = qls[w*4+0][k], q1 = qls[w*4+1][k], q2 = qls[w*4+2][k], q3 = qls[w*4+3][k];
#pragma unroll
      for (int cc = 0; cc < 4; ++cc){
        float wv = Wp[(size_t)k*256 + cc*64];
        acc[cc][0] += q0*wv; acc[cc][1] += q1*wv; acc[cc][2] += q2*wv; acc[cc][3] += q3*wv;
      }
    }
#pragma unroll
    for (int cc = 0; cc < 4; ++cc)
#pragma unroll
      for (int rr = 0; rr < 4; ++rr){
        int s = w*4 + rr;
        qp[(((size_t)b*H_ + h)*S_ + s)*D_ + cc*64 + lane] = f2bf(SCALE_ * acc[cc][rr]);
      }
  }
}

// ---------------- flash (R12 structure; axPart now bf16) ----------------
__global__ __launch_bounds__(512, 2) void k_flash(
    const unsigned short* __restrict__ xn, const unsigned short* __restrict__ xnT,
    const unsigned short* __restrict__ qp, const float* __restrict__ qb,
    float* __restrict__ mPart, float* __restrict__ lPart, unsigned short* __restrict__ axPart)
{
  __shared__ __align__(16) char lds[81920];  // xn 32K | xnT 32K @32768 | P 8x2K @65536
  const int ch = blockIdx.x;
  const int b  = blockIdx.y;
  const int t  = threadIdx.x;
  const int lane = t & 63;
  const int w  = t >> 6;          // wave == head
  const int g  = lane >> 4;       // 0..3
  const int c  = lane & 15;       // 0..15
  const int n0 = ch * NCHUNK_;

  short8 aq[8];
#pragma unroll
  for (int ks = 0; ks < 8; ++ks)
    aq[ks] = *(const short8*)&qp[(((size_t)b*H_ + w)*S_ + c)*D_ + ks*32 + g*8];
  float qbr[4];
#pragma unroll
  for (int r = 0; r < 4; ++r)
    qbr[r] = qb[((size_t)b*H_ + w)*S_ + g*4 + r];

  f32x4 accX[16];
#pragma unroll
  for (int i = 0; i < 16; ++i){ f32x4 z = {0.f,0.f,0.f,0.f}; accX[i] = z; }
  float mrun[4] = {-1e30f,-1e30f,-1e30f,-1e30f};
  float lrun[4] = {0.f,0.f,0.f,0.f};

  auto ISSUE = [&](int tl){
#pragma unroll
    for (int j = 0; j < 4; ++j){           // xn rows: 2 rows per inst
      int rl = w*8 + j*2 + (lane >> 5);
      int cs = (lane & 31) ^ (rl & 7);     // pre-swizzled source chunk
      gld16(&xn[((size_t)b*N_ + n0 + tl*64 + rl)*D_ + cs*8],
            lds + (w*8 + j*2)*512);
    }
#pragma unroll
    for (int j = 0; j < 4; ++j){           // xnT rows: 8 rows per inst
      int dl = w*32 + j*8 + (lane >> 3);
      int cs = (lane & 7) ^ (dl & 7);
      gld16(&xnT[((size_t)b*D_ + dl)*N_ + n0 + tl*64 + cs*8],
            lds + 32768 + (w*32 + j*8)*128);
    }
  };

  ISSUE(0);
#pragma unroll 1
  for (int tl = 0; tl < 8; ++tl){
    __syncthreads();                       // drains vmcnt: tile ready for all waves
    const char* xb  = lds;
    const char* xbT = lds + 32768;
    char* pbuf = lds + 65536 + w*2048;
    f32x4 lg[4];
#pragma unroll
    for (int nf = 0; nf < 4; ++nf){ f32x4 z = {0.f,0.f,0.f,0.f}; lg[nf] = z; }
#pragma unroll
    for (int ks = 0; ks < 8; ++ks){
#pragma unroll
      for (int nf = 0; nf < 4; ++nf){
        int n = nf*16 + c;
        short8 bf = *(const short8*)(xb + n*512 + (((ks*32 + g*8)*2) ^ ((n & 7) << 4)));
        lg[nf] = __builtin_amdgcn_mfma_f32_16x16x32_bf16(aq[ks], bf, lg[nf], 0, 0, 0);
      }
    }
    float tmax[4];
#pragma unroll
    for (int r = 0; r < 4; ++r){
      lg[0][r] += qbr[r]; lg[1][r] += qbr[r]; lg[2][r] += qbr[r]; lg[3][r] += qbr[r];
      tmax[r] = fmaxf(fmaxf(lg[0][r], lg[1][r]), fmaxf(lg[2][r], lg[3][r]));
      tmax[r] = fmaxf(tmax[r], __shfl_xor(tmax[r], 1));
      tmax[r] = fmaxf(tmax[r], __shfl_xor(tmax[r], 2));
      tmax[r] = fmaxf(tmax[r], __shfl_xor(tmax[r], 4));
      tmax[r] = fmaxf(tmax[r], __shfl_xor(tmax[r], 8));
    }
    float fac[4], psum[4];
#pragma unroll
    for (int r = 0; r < 4; ++r){
      float mnew = fmaxf(mrun[r], tmax[r]);
      fac[r] = __expf(mrun[r] - mnew);
      mrun[r] = mnew;
      lrun[r] *= fac[r];
      psum[r] = 0.f;
    }
#pragma unroll
    for (int i = 0; i < 16; ++i){
      accX[i][0] *= fac[0]; accX[i][1] *= fac[1]; accX[i][2] *= fac[2]; accX[i][3] *= fac[3];
    }
#pragma unroll
    for (int nf = 0; nf < 4; ++nf){
#pragma unroll
      for (int r = 0; r < 4; ++r){
        float p = __expf(lg[nf][r] - mrun[r]);
        psum[r] += p;
        int row = g*4 + r;
        *(unsigned short*)(pbuf + row*128 + (((nf*16 + c)*2) ^ ((row & 7) << 4))) = f2bf(p);
      }
    }
#pragma unroll
    for (int r = 0; r < 4; ++r){
      psum[r] += __shfl_xor(psum[r], 1);
      psum[r] += __shfl_xor(psum[r], 2);
      psum[r] += __shfl_xor(psum[r], 4);
      psum[r] += __shfl_xor(psum[r], 8);
      lrun[r] += psum[r];
    }
#pragma unroll
    for (int ks = 0; ks < 2; ++ks){
      short8 pa = *(const short8*)(pbuf + c*128 + (((ks*32 + g*8)*2) ^ ((c & 7) << 4)));
#pragma unroll
      for (int df = 0; df < 16; ++df){
        int d = df*16 + c;
        short8 bt = *(const short8*)(xbT + d*128 + (((ks*32 + g*8)*2) ^ ((d & 7) << 4)));
        accX[df] = __builtin_amdgcn_mfma_f32_16x16x32_bf16(pa, bt, accX[df], 0, 0, 0);
      }
    }
    __syncthreads();                       // all waves done reading tile
    if (tl < 7) ISSUE(tl + 1);             // overwrite with next tile (async)
  }
  size_t base = (((size_t)b*CH_ + ch)*H_ + w)*S_;
  if (c == 0){
#pragma unroll
    for (int r = 0; r < 4; ++r){
      mPart[base + g*4 + r] = mrun[r];
      lPart[base + g*4 + r] = lrun[r];
    }
  }
  size_t base3 = base * D_;
#pragma unroll
  for (int df = 0; df < 16; ++df){
#pragma unroll
    for (int r = 0; r < 4; ++r){
      axPart[base3 + df*256 + r*64 + lane] = f2bf(accX[df][r]);
    }
  }
}

// ---------------- combine chunks + Wv projection -> upd [B][S][DI]  (axPart bf16) ----------------
__global__ __launch_bounds__(256) void k_combine(
    const float* __restrict__ mPart, const float* __restrict__ lPart,
    const unsigned short* __restrict__ axPart,
    const float* __restrict__ WvT, const float* __restrict__ bv, float* __restrict__ upd)
{
  __shared__ __align__(16) float av[4][256];
  const int id = blockIdx.x;              // 1024 = b*32 + h*4 + sq
  const int b  = id >> 5;
  const int h  = (id >> 2) & 7;
  const int sq = id & 3;
  const int t = threadIdx.x;
  const int sl = t >> 6;
  const int lane = t & 63;
  const int s = sq*4 + sl;
  const int sg = s >> 2, sr = s & 3;
  const size_t pb = (((size_t)b*CH_)*H_ + h)*S_ + s;
  float mg = -1e30f;
  float mv[8], lv[8];
#pragma unroll
  for (int k = 0; k < 8; ++k){
    mv[k] = mPart[pb + (size_t)k*128];
    lv[k] = lPart[pb + (size_t)k*128];
    mg = fmaxf(mg, mv[k]);
  }
  const size_t off_s = (size_t)sr*64 + sg*16 + (lane>>2)*256 + (lane&3)*4;
  float L = 0.f, ax0 = 0.f, ax1 = 0.f, ax2 = 0.f, ax3 = 0.f;
#pragma unroll
  for (int k = 0; k < 8; ++k){
    float wgt = __expf(mv[k] - mg);
    L += lv[k]*wgt;
    size_t base3 = ((((size_t)b*CH_ + k)*H_ + h)*S_) * D_;
    uint2 a2 = *(const uint2*)&axPart[base3 + off_s];
    ax0 += bf2f((unsigned short)(a2.x & 0xffffu)) * wgt;
    ax1 += bf2f((unsigned short)(a2.x >> 16))     * wgt;
    ax2 += bf2f((unsigned short)(a2.y & 0xffffu)) * wgt;
    ax3 += bf2f((unsigned short)(a2.y >> 16))     * wgt;
  }
  float inv = 1.f / L;
  av[sl][lane*4+0] = ax0*inv; av[sl][lane*4+1] = ax1*inv;
  av[sl][lane*4+2] = ax2*inv; av[sl][lane*4+3] = ax3*inv;
  __syncthreads();
  float acc = bv[h*64 + lane];
  for (int d = 0; d < 256; d += 2){
    float2 a2 = *(const float2*)&av[sl][d];
    acc += a2.x * WvT[(size_t)d*512     + h*64 + lane];
    acc += a2.y * WvT[(size_t)(d+1)*512 + h*64 + lane];
  }
  upd[((size_t)b*S_ + s)*DI_ + h*64 + lane] = acc;
}

// ============ post chain (exact R7/R12): wave = 1 row, lane = 1 out col ============
__global__ __launch_bounds__(256) void k_sA(
    const float* __restrict__ upd, const float* __restrict__ WcT,
    const float* __restrict__ bc, float* __restrict__ updc)
{
  __shared__ __align__(16) float act[4][512];
  const int lane = threadIdx.x & 63, w = threadIdx.x >> 6;
  const int row = blockIdx.x*4 + w;
  const int col = blockIdx.y*64 + lane;
  *(float4*)&act[w][lane*8]     = *(const float4*)&upd[(size_t)row*DI_ + lane*8];
  *(float4*)&act[w][lane*8 + 4] = *(const float4*)&upd[(size_t)row*DI_ + lane*8 + 4];
  const float* Wp = WcT + col;
  float acc = 0.f;
#pragma unroll 4
  for (int k4 = 0; k4 < 128; ++k4){
    float4 a = *(const float4*)&act[w][k4*4];
    acc += a.x * Wp[(size_t)(k4*4+0)*256];
    acc += a.y * Wp[(size_t)(k4*4+1)*256];
    acc += a.z * Wp[(size_t)(k4*4+2)*256];
    acc += a.w * Wp[(size_t)(k4*4+3)*256];
  }
  updc[(size_t)row*D_ + col] = acc + bc[col];
}

__global__ __launch_bounds__(256) void k_sB(
    const float* __restrict__ updc, const float* __restrict__ slots,
    const float* __restrict__ wihT, const float* __restrict__ whhT,
    const float* __restrict__ bih, const float* __restrict__ bhh,
    float* __restrict__ snl)
{
  __shared__ __align__(16) float au[4][256];
  __shared__ __align__(16) float as[4][256];
  const int lane = threadIdx.x & 63, w = threadIdx.x >> 6;
  const int row = blockIdx.x*4 + w;
  const int d   = blockIdx.y*64 + lane;
  *(float4*)&au[w][lane*4] = *(const float4*)&updc[(size_t)row*D_ + lane*4];
  *(float4*)&as[w][lane*4] = *(const float4*)&slots[(size_t)row*D_ + lane*4];
  const float* Wi = wihT + d;
  const float* Wh = whhT + d;
  float air=0.f, aiz=0.f, ain=0.f, ahr=0.f, ahz=0.f, ahn=0.f;
#pragma unroll 2
  for (int k4 = 0; k4 < 64; ++k4){
    float4 u = *(const float4*)&au[w][k4*4];
    float4 s = *(const float4*)&as[w][k4*4];
#pragma unroll
    for (int j = 0; j < 4; ++j){
      int k = k4*4 + j;
      float uv = (j==0)?u.x:(j==1)?u.y:(j==2)?u.z:u.w;
      float sv = (j==0)?s.x:(j==1)?s.y:(j==2)?s.z:s.w;
      air += uv * Wi[(size_t)k*768];
      aiz += uv * Wi[(size_t)k*768 + 256];
      ain += uv * Wi[(size_t)k*768 + 512];
      ahr += sv * Wh[(size_t)k*768];
      ahz += sv * Wh[(size_t)k*768 + 256];
      ahn += sv * Wh[(size_t)k*768 + 512];
    }
  }
  float ir = air + bih[d]     + ahr + bhh[d];
  float iz = aiz + bih[256+d] + ahz + bhh[256+d];
  float rg = 1.f/(1.f + __expf(-ir));
  float zg = 1.f/(1.f + __expf(-iz));
  float ng = tanhf(ain + bih[512+d] + rg*(ahn + bhh[512+d]));
  snl[(size_t)row*D_ + d] = (1.f - zg)*ng + zg*as[w][d];
}

__global__ __launch_bounds__(256) void k_sC(
    const float* __restrict__ snl, const float* __restrict__ lfg, const float* __restrict__ lfb,
    const float* __restrict__ W1T, const float* __restrict__ b1, float* __restrict__ h1)
{
  __shared__ __align__(16) float a[4][256];
  const int lane = threadIdx.x & 63, w = threadIdx.x >> 6;
  const int row = blockIdx.x*4 + w;
  const int o   = blockIdx.y*64 + lane;
  float4 v = *(const float4*)&snl[(size_t)row*D_ + lane*4];
  float s = v.x + v.y + v.z + v.w;
  float q = v.x*v.x + v.y*v.y + v.z*v.z + v.w*v.w;
#pragma unroll
  for (int m = 1; m < 64; m <<= 1){ s += __shfl_xor(s, m); q += __shfl_xor(q, m); }
  float mean = s * 0.00390625f;
  float var  = q * 0.00390625f - mean*mean;
  float rs = rsqrtf(var + 1e-5f);
  float4 gv = *(const float4*)&lfg[lane*4];
  float4 bv = *(const float4*)&lfb[lane*4];
  a[w][lane*4+0] = (v.x-mean)*rs*gv.x + bv.x;
  a[w][lane*4+1] = (v.y-mean)*rs*gv.y + bv.y;
  a[w][lane*4+2] = (v.z-mean)*rs*gv.z + bv.z;
  a[w][lane*4+3] = (v.w-mean)*rs*gv.w + bv.w;
  const float* Wp = W1T + o;
  float acc = 0.f;
#pragma unroll 4
  for (int k4 = 0; k4 < 64; ++k4){
    float4 av = *(const float4*)&a[w][k4*4];
    acc += av.x * Wp[(size_t)(k4*4+0)*1024];
    acc += av.y * Wp[(size_t)(k4*4+1)*1024];
    acc += av.z * Wp[(size_t)(k4*4+2)*1024];
    acc += av.w * Wp[(size_t)(k4*4+3)*1024];
  }
  h1[(size_t)row*HID_ + o] = fmaxf(acc + b1[o], 0.f);
}

__global__ __launch_bounds__(256) void k_sD(
    const float* __restrict__ h1, const float* __restrict__ snl,
    const float* __restrict__ W2T, const float* __restrict__ b2, float* __restrict__ dst)
{
  __shared__ __align__(16) float a[4][1024];
  const int lane = threadIdx.x & 63, w = threadIdx.x >> 6;
  const int row = blockIdx.x*4 + w;
  const int o   = blockIdx.y*64 + lane;
#pragma unroll
  for (int j = 0; j < 4; ++j)
    *(float4*)&a[w][lane*16 + j*4] = *(const float4*)&h1[(size_t)row*HID_ + lane*16 + j*4];
  const float* Wp = W2T + o;
  float acc = 0.f;
#pragma unroll 4
  for (int k4 = 0; k4 < 256; ++k4){
    float4 av = *(const float4*)&a[w][k4*4];
    acc += av.x * Wp[(size_t)(k4*4+0)*256];
    acc += av.y * Wp[(size_t)(k4*4+1)*256];
    acc += av.z * Wp[(size_t)(k4*4+2)*256];
    acc += av.w * Wp[(size_t)(k4*4+3)*256];
  }
  dst[(size_t)row*D_ + o] = snl[(size_t)row*D_ + o] + acc + b2[o];
}

extern "C" void kernel_launch(void* const* d_in, const int* in_sizes, int n_in,
                              void* d_out, int out_size, void* d_ws, size_t ws_size,
                              hipStream_t stream)
{
  const float* x       = (const float*)d_in[0];
  const float* noise   = (const float*)d_in[1];
  const float* mu      = (const float*)d_in[2];
  const float* lsig    = (const float*)d_in[3];
  const float* ln_in_g = (const float*)d_in[4];
  const float* ln_in_b = (const float*)d_in[5];
  const float* ln_s_g  = (const float*)d_in[6];
  const float* ln_s_b  = (const float*)d_in[7];
  const float* ln_ff_g = (const float*)d_in[8];
  const float* ln_ff_b = (const float*)d_in[9];
  const float* Wq  = (const float*)d_in[10]; const float* bq  = (const float*)d_in[11];
  const float* Wk  = (const float*)d_in[12]; const float* bk  = (const float*)d_in[13];
  const float* Wv  = (const float*)d_in[14]; const float* bv  = (const float*)d_in[15];
  const float* Wc  = (const float*)d_in[16]; const float* bc  = (const float*)d_in[17];
  const float* wih = (const float*)d_in[18]; const float* whh = (const float*)d_in[19];
  const float* bih = (const float*)d_in[20]; const float* bhh = (const float*)d_in[21];
  const float* W1  = (const float*)d_in[22]; const float* b1  = (const float*)d_in[23];
  const float* W2  = (const float*)d_in[24]; const float* b2  = (const float*)d_in[25];

  char* ws = (char*)d_ws;
  unsigned short* xn  = (unsigned short*)(ws + 0);
  unsigned short* xnT = (unsigned short*)(ws + 67108864);
  float* slots = (float*)(ws + 134217728);
  unsigned short* qp = (unsigned short*)(ws + 134742016);
  float* qb   = (float*)(ws + 136839168);
  float* mP   = (float*)(ws + 136855552);
  float* lP   = (float*)(ws + 136986624);
  unsigned short* axP = (unsigned short*)(ws + 137117696);   // bf16 now (uses half the region)
  float* upd  = (float*)(ws + 170672128);
  float* WqT  = (float*)(ws + 171720704);
  float* WvT  = (float*)(ws + 172244992);
  float* WcT  = (float*)(ws + 172769280);
  float* wihT = (float*)(ws + 173293568);
  float* whhT = (float*)(ws + 174080000);
  float* W1T  = (float*)(ws + 174866432);
  float* W2T  = (float*)(ws + 175915008);
  // overlays: post-chain intermediates live past the bf16 axP extent (axP now ends at +153894912)
  float* updc = (float*)(ws + 153894912);
  float* snl  = (float*)(ws + 154419200);
  float* h1   = (float*)(ws + 154943488);

  if (ws_size < (size_t)176963584ull){
    k_badws<<<512, 256, 0, stream>>>((float*)d_out);
    return;
  }

  k_init_slots<<<512, 256, 0, stream>>>(noise, mu, lsig, slots);
  k_ln_x<<<2048, 256, 0, stream>>>(x, ln_in_g, ln_in_b, xn, xnT);
  k_tr_all<<<1280, dim3(32, 8), 0, stream>>>(Wq, Wv, Wc, wih, whh, W1, W2,
                                             WqT, WvT, WcT, wihT, whhT, W1T, W2T);

  for (int it = 0; it < 3; ++it){
    k_pre2<<<256, 256, 0, stream>>>(slots, ln_s_g, ln_s_b, WqT, bq, Wk, bk, qp, qb);
    k_flash<<<dim3(CH_, B_), 512, 0, stream>>>(xn, xnT, qp, qb, mP, lP, axP);
    k_combine<<<1024, 256, 0, stream>>>(mP, lP, axP, WvT, bv, upd);
    k_sA<<<dim3(128, 4),  256, 0, stream>>>(upd, WcT, bc, updc);
    k_sB<<<dim3(128, 4),  256, 0, stream>>>(updc, slots, wihT, whhT, bih, bhh, snl);
    k_sC<<<dim3(128, 16), 256, 0, stream>>>(snl, ln_ff_g, ln_ff_b, W1T, b1, h1);
    k_sD<<<dim3(128, 4),  256, 0, stream>>>(h1, snl, W2T, b2, (it == 2) ? (float*)d_out : slots);
  }
}

// Round 15
// 564.425 us; speedup vs baseline: 1.0451x; 1.0451x over previous
//
#include <hip/hip_runtime.h>
#include <stdint.h>

#define B_   32
#define N_   4096
#define D_   256
#define H_   8
#define S_   16
#define DI_  512
#define HID_ 1024
#define CH_  8
#define NCHUNK_ 512
#define SCALE_ 0.0625f

typedef short  short8 __attribute__((ext_vector_type(8)));
typedef float  f32x4  __attribute__((ext_vector_type(4)));

__device__ __forceinline__ unsigned short f2bf(float x){
  union { float f; unsigned u; } v; v.f = x;
  unsigned r = v.u + 0x7FFFu + ((v.u >> 16) & 1u);
  return (unsigned short)(r >> 16);
}

__device__ __forceinline__ void gld16(const void* g, void* l){
  __builtin_amdgcn_global_load_lds(
      (const __attribute__((address_space(1))) unsigned int*)g,
      (__attribute__((address_space(3))) unsigned int*)l, 16, 0, 0);
}

// ---------------- ws too small sentinel ----------------
__global__ void k_badws(float* out){ out[blockIdx.x*256 + threadIdx.x] = 1e9f; }

// ---------------- slots init ----------------
__global__ __launch_bounds__(256) void k_init_slots(
    const float* __restrict__ noise, const float* __restrict__ mu,
    const float* __restrict__ lsig, float* __restrict__ slots)
{
  int i = blockIdx.x*256 + threadIdx.x;   // < 131072
  int d = i & 255;
  slots[i] = mu[d] + expf(lsig[d]) * noise[i];
}

// ---------------- all 7 weight transposes in ONE launch (proven R10-R12) ----------------
__global__ __launch_bounds__(256) void k_tr_all(
    const float* __restrict__ Wq,  const float* __restrict__ Wv,  const float* __restrict__ Wc,
    const float* __restrict__ wih, const float* __restrict__ whh,
    const float* __restrict__ W1,  const float* __restrict__ W2,
    float* __restrict__ WqT, float* __restrict__ WvT, float* __restrict__ WcT,
    float* __restrict__ wihT, float* __restrict__ whhT,
    float* __restrict__ W1T, float* __restrict__ W2T)
{
  __shared__ float t[32][33];
  const int id = blockIdx.x;
  const float* src; float* dst; int R, C, bx, by;
  if      (id < 128) { src=Wq;  dst=WqT;  R=512;  C=256;  int s=id;      bx=s&7;  by=s>>3; }
  else if (id < 256) { src=Wv;  dst=WvT;  R=512;  C=256;  int s=id-128;  bx=s&7;  by=s>>3; }
  else if (id < 384) { src=Wc;  dst=WcT;  R=256;  C=512;  int s=id-256;  bx=s&15; by=s>>4; }
  else if (id < 576) { src=wih; dst=wihT; R=768;  C=256;  int s=id-384;  bx=s&7;  by=s>>3; }
  else if (id < 768) { src=whh; dst=whhT; R=768;  C=256;  int s=id-576;  bx=s&7;  by=s>>3; }
  else if (id < 1024){ src=W1;  dst=W1T;  R=1024; C=256;  int s=id-768;  bx=s&7;  by=s>>3; }
  else               { src=W2;  dst=W2T;  R=256;  C=1024; int s=id-1024; bx=s&31; by=s>>5; }
  int c0 = bx*32, r0 = by*32;
  int tx = threadIdx.x, ty = threadIdx.y;   // 32 x 8
  for (int j = 0; j < 32; j += 8){
    int r = r0 + ty + j, c = c0 + tx;
    if (r < R && c < C) t[ty+j][tx] = src[(size_t)r*C + c];
  }
  __syncthreads();
  for (int j = 0; j < 32; j += 8){
    int c = c0 + ty + j, r = r0 + tx;
    if (c < C && r < R) dst[(size_t)c*R + r] = t[tx][ty+j];
  }
}

// ---------------- LN(x) -> xn bf16 [B][N][D] and xnT bf16 [B][D][N]  (exact R12) ----------------
__global__ __launch_bounds__(256) void k_ln_x(
    const float* __restrict__ x, const float* __restrict__ g, const float* __restrict__ bb,
    unsigned short* __restrict__ xn, unsigned short* __restrict__ xnT)
{
  __shared__ __align__(16) char tile[32768];   // 64 rows x 256 bf16, swizzled
  const int blk = blockIdx.x;
  const int b  = blk >> 6;
  const int n0 = (blk & 63) * 64;
  const int t = threadIdx.x;
  const int lane = t & 63;
  const int w = t >> 6;
  float4 gv = *(const float4*)&g[lane*4];
  float4 bv = *(const float4*)&bb[lane*4];
#pragma unroll 1
  for (int it = 0; it < 16; ++it){
    const int nl = w*16 + it;
    const size_t row = (size_t)b*N_ + n0 + nl;
    float4 xv = *(const float4*)&x[row*256 + lane*4];
    float s = xv.x + xv.y + xv.z + xv.w;
    float q = xv.x*xv.x + xv.y*xv.y + xv.z*xv.z + xv.w*xv.w;
#pragma unroll
    for (int m = 1; m < 64; m <<= 1){ s += __shfl_xor(s, m); q += __shfl_xor(q, m); }
    float mean = s * 0.00390625f;
    float var  = q * 0.00390625f - mean*mean;
    float rs = rsqrtf(var + 1e-5f);
    unsigned short u0 = f2bf((xv.x-mean)*rs*gv.x + bv.x);
    unsigned short u1 = f2bf((xv.y-mean)*rs*gv.y + bv.y);
    unsigned short u2 = f2bf((xv.z-mean)*rs*gv.z + bv.z);
    unsigned short u3 = f2bf((xv.w-mean)*rs*gv.w + bv.w);
    uint2 pk; pk.x = (unsigned)u0 | ((unsigned)u1 << 16); pk.y = (unsigned)u2 | ((unsigned)u3 << 16);
    *(uint2*)&xn[row*256 + lane*4] = pk;
    *(uint2*)(tile + nl*512 + ((lane*8) ^ ((nl & 7) << 4))) = pk;
  }
  __syncthreads();
#pragma unroll 1
  for (int j = 0; j < 32; ++j){
    int flat = j*256 + t;           // 8192 dwords
    int d  = flat >> 5;             // 0..255
    int np = (flat & 31) * 2;       // n pair base
    unsigned short lo = *(const unsigned short*)(tile + np*512     + ((2*d) ^ ((np     & 7) << 4)));
    unsigned short hi = *(const unsigned short*)(tile + (np+1)*512 + ((2*d) ^ (((np+1) & 7) << 4)));
    *(unsigned*)&xnT[((size_t)b*D_ + d)*N_ + n0 + np] = (unsigned)lo | ((unsigned)hi << 16);
  }
}

// ---------------- preA: LN(slots) + ql = sn @ WqT + bq  (exact R7/R12) ----------------
__global__ __launch_bounds__(256) void k_preA(
    const float* __restrict__ slots, const float* __restrict__ lsg, const float* __restrict__ lsb,
    const float* __restrict__ WqT, const float* __restrict__ bq, float* __restrict__ ql)
{
  __shared__ __align__(16) float a[4][256];
  const int lane = threadIdx.x & 63, w = threadIdx.x >> 6;
  const int row = blockIdx.x*4 + w;            // 0..511
  const int o   = blockIdx.y*64 + lane;        // 0..511
  float4 v = *(const float4*)&slots[(size_t)row*D_ + lane*4];
  float s = v.x + v.y + v.z + v.w;
  float q = v.x*v.x + v.y*v.y + v.z*v.z + v.w*v.w;
#pragma unroll
  for (int m = 1; m < 64; m <<= 1){ s += __shfl_xor(s, m); q += __shfl_xor(q, m); }
  float mean = s * 0.00390625f;
  float var  = q * 0.00390625f - mean*mean;
  float rs = rsqrtf(var + 1e-5f);
  float4 gv = *(const float4*)&lsg[lane*4];
  float4 bv = *(const float4*)&lsb[lane*4];
  a[w][lane*4+0] = (v.x-mean)*rs*gv.x + bv.x;
  a[w][lane*4+1] = (v.y-mean)*rs*gv.y + bv.y;
  a[w][lane*4+2] = (v.z-mean)*rs*gv.z + bv.z;
  a[w][lane*4+3] = (v.w-mean)*rs*gv.w + bv.w;
  const float* Wp = WqT + o;
  float acc = 0.f;
#pragma unroll 4
  for (int k4 = 0; k4 < 64; ++k4){
    float4 av = *(const float4*)&a[w][k4*4];
    acc += av.x * Wp[(size_t)(k4*4+0)*512];
    acc += av.y * Wp[(size_t)(k4*4+1)*512];
    acc += av.z * Wp[(size_t)(k4*4+2)*512];
    acc += av.w * Wp[(size_t)(k4*4+3)*512];
  }
  ql[(size_t)row*DI_ + o] = acc + bq[o];
}

// ---------------- preB: qp = SCALE*(ql_h @ Wk_h), qb = SCALE*(ql_h . bk_h)  (exact R7/R12) ----------------
__global__ __launch_bounds__(256) void k_preB(
    const float* __restrict__ ql, const float* __restrict__ Wk, const float* __restrict__ bk,
    unsigned short* __restrict__ qp, float* __restrict__ qb)
{
  __shared__ __align__(16) float qs[16][64];
  const int id = blockIdx.x;          // 256 = b*8 + h
  const int b  = id >> 3;
  const int h  = id & 7;
  const int cb = blockIdx.y;          // 0..3
  const int c0 = cb*64;
  const int t = threadIdx.x;
  const int lane = t & 63, w = t >> 6;
  {
    int flat = t*4;                   // 1024 floats = 16 rows x 64
    int s = flat >> 6, k = flat & 63;
    *(float4*)&qs[s][k] = *(const float4*)&ql[((size_t)(b*S_ + s))*DI_ + h*64 + k];
  }
  __syncthreads();
  if (cb == 0){
    float bkv = bk[h*64 + lane];
#pragma unroll
    for (int r = 0; r < 4; ++r){
      int s = w*4 + r;
      float v = qs[s][lane] * bkv;
#pragma unroll
      for (int m = 1; m < 64; m <<= 1) v += __shfl_xor(v, m);
      if (lane == 0) qb[((size_t)b*H_ + h)*S_ + s] = v * SCALE_;
    }
  }
  float acc[4] = {};
  const float* Wp = Wk + (size_t)(h*64)*256 + c0 + lane;
#pragma unroll 4
  for (int k = 0; k < 64; ++k){
    float wv = Wp[(size_t)k*256];
    acc[0] += qs[w*4+0][k] * wv;
    acc[1] += qs[w*4+1][k] * wv;
    acc[2] += qs[w*4+2][k] * wv;
    acc[3] += qs[w*4+3][k] * wv;
  }
#pragma unroll
  for (int r = 0; r < 4; ++r){
    int s = w*4 + r;
    qp[(((size_t)b*H_ + h)*S_ + s)*D_ + c0 + lane] = f2bf(SCALE_ * acc[r]);
  }
}

// ---------------- flash (exact R12): single-buffered 80 KB, async gld16, 2 blocks/CU ----------------
__global__ __launch_bounds__(512, 2) void k_flash(
    const unsigned short* __restrict__ xn, const unsigned short* __restrict__ xnT,
    const unsigned short* __restrict__ qp, const float* __restrict__ qb,
    float* __restrict__ mPart, float* __restrict__ lPart, float* __restrict__ axPart)
{
  __shared__ __align__(16) char lds[81920];  // xn 32K | xnT 32K @32768 | P 8x2K @65536
  const int ch = blockIdx.x;
  const int b  = blockIdx.y;
  const int t  = threadIdx.x;
  const int lane = t & 63;
  const int w  = t >> 6;          // wave == head
  const int g  = lane >> 4;       // 0..3
  const int c  = lane & 15;       // 0..15
  const int n0 = ch * NCHUNK_;

  short8 aq[8];
#pragma unroll
  for (int ks = 0; ks < 8; ++ks)
    aq[ks] = *(const short8*)&qp[(((size_t)b*H_ + w)*S_ + c)*D_ + ks*32 + g*8];
  float qbr[4];
#pragma unroll
  for (int r = 0; r < 4; ++r)
    qbr[r] = qb[((size_t)b*H_ + w)*S_ + g*4 + r];

  f32x4 accX[16];
#pragma unroll
  for (int i = 0; i < 16; ++i){ f32x4 z = {0.f,0.f,0.f,0.f}; accX[i] = z; }
  float mrun[4] = {-1e30f,-1e30f,-1e30f,-1e30f};
  float lrun[4] = {0.f,0.f,0.f,0.f};

  auto ISSUE = [&](int tl){
#pragma unroll
    for (int j = 0; j < 4; ++j){           // xn rows: 2 rows per inst
      int rl = w*8 + j*2 + (lane >> 5);
      int cs = (lane & 31) ^ (rl & 7);     // pre-swizzled source chunk
      gld16(&xn[((size_t)b*N_ + n0 + tl*64 + rl)*D_ + cs*8],
            lds + (w*8 + j*2)*512);
    }
#pragma unroll
    for (int j = 0; j < 4; ++j){           // xnT rows: 8 rows per inst
      int dl = w*32 + j*8 + (lane >> 3);
      int cs = (lane & 7) ^ (dl & 7);
      gld16(&xnT[((size_t)b*D_ + dl)*N_ + n0 + tl*64 + cs*8],
            lds + 32768 + (w*32 + j*8)*128);
    }
  };

  ISSUE(0);
#pragma unroll 1
  for (int tl = 0; tl < 8; ++tl){
    __syncthreads();                       // drains vmcnt: tile ready for all waves
    const char* xb  = lds;
    const char* xbT = lds + 32768;
    char* pbuf = lds + 65536 + w*2048;
    f32x4 lg[4];
#pragma unroll
    for (int nf = 0; nf < 4; ++nf){ f32x4 z = {0.f,0.f,0.f,0.f}; lg[nf] = z; }
#pragma unroll
    for (int ks = 0; ks < 8; ++ks){
#pragma unroll
      for (int nf = 0; nf < 4; ++nf){
        int n = nf*16 + c;
        short8 bf = *(const short8*)(xb + n*512 + (((ks*32 + g*8)*2) ^ ((n & 7) << 4)));
        lg[nf] = __builtin_amdgcn_mfma_f32_16x16x32_bf16(aq[ks], bf, lg[nf], 0, 0, 0);
      }
    }
    float tmax[4];
#pragma unroll
    for (int r = 0; r < 4; ++r){
      lg[0][r] += qbr[r]; lg[1][r] += qbr[r]; lg[2][r] += qbr[r]; lg[3][r] += qbr[r];
      tmax[r] = fmaxf(fmaxf(lg[0][r], lg[1][r]), fmaxf(lg[2][r], lg[3][r]));
      tmax[r] = fmaxf(tmax[r], __shfl_xor(tmax[r], 1));
      tmax[r] = fmaxf(tmax[r], __shfl_xor(tmax[r], 2));
      tmax[r] = fmaxf(tmax[r], __shfl_xor(tmax[r], 4));
      tmax[r] = fmaxf(tmax[r], __shfl_xor(tmax[r], 8));
    }
    float fac[4], psum[4];
#pragma unroll
    for (int r = 0; r < 4; ++r){
      float mnew = fmaxf(mrun[r], tmax[r]);
      fac[r] = __expf(mrun[r] - mnew);
      mrun[r] = mnew;
      lrun[r] *= fac[r];
      psum[r] = 0.f;
    }
#pragma unroll
    for (int i = 0; i < 16; ++i){
      accX[i][0] *= fac[0]; accX[i][1] *= fac[1]; accX[i][2] *= fac[2]; accX[i][3] *= fac[3];
    }
#pragma unroll
    for (int nf = 0; nf < 4; ++nf){
#pragma unroll
      for (int r = 0; r < 4; ++r){
        float p = __expf(lg[nf][r] - mrun[r]);
        psum[r] += p;
        int row = g*4 + r;
        *(unsigned short*)(pbuf + row*128 + (((nf*16 + c)*2) ^ ((row & 7) << 4))) = f2bf(p);
      }
    }
#pragma unroll
    for (int r = 0; r < 4; ++r){
      psum[r] += __shfl_xor(psum[r], 1);
      psum[r] += __shfl_xor(psum[r], 2);
      psum[r] += __shfl_xor(psum[r], 4);
      psum[r] += __shfl_xor(psum[r], 8);
      lrun[r] += psum[r];
    }
#pragma unroll
    for (int ks = 0; ks < 2; ++ks){
      short8 pa = *(const short8*)(pbuf + c*128 + (((ks*32 + g*8)*2) ^ ((c & 7) << 4)));
#pragma unroll
      for (int df = 0; df < 16; ++df){
        int d = df*16 + c;
        short8 bt = *(const short8*)(xbT + d*128 + (((ks*32 + g*8)*2) ^ ((d & 7) << 4)));
        accX[df] = __builtin_amdgcn_mfma_f32_16x16x32_bf16(pa, bt, accX[df], 0, 0, 0);
      }
    }
    __syncthreads();                       // all waves done reading tile
    if (tl < 7) ISSUE(tl + 1);             // overwrite with next tile (async)
  }
  size_t base = (((size_t)b*CH_ + ch)*H_ + w)*S_;
  if (c == 0){
#pragma unroll
    for (int r = 0; r < 4; ++r){
      mPart[base + g*4 + r] = mrun[r];
      lPart[base + g*4 + r] = lrun[r];
    }
  }
  size_t base3 = base * D_;
#pragma unroll
  for (int df = 0; df < 16; ++df){
#pragma unroll
    for (int r = 0; r < 4; ++r){
      axPart[base3 + df*256 + r*64 + lane] = accX[df][r];
    }
  }
}

// ---------------- combine chunks + Wv projection -> upd [B][S][DI]  (exact R12) ----------------
__global__ __launch_bounds__(256) void k_combine(
    const float* __restrict__ mPart, const float* __restrict__ lPart, const float* __restrict__ axPart,
    const float* __restrict__ WvT, const float* __restrict__ bv, float* __restrict__ upd)
{
  __shared__ __align__(16) float av[4][256];
  const int id = blockIdx.x;              // 1024 = b*32 + h*4 + sq
  const int b  = id >> 5;
  const int h  = (id >> 2) & 7;
  const int sq = id & 3;
  const int t = threadIdx.x;
  const int sl = t >> 6;
  const int lane = t & 63;
  const int s = sq*4 + sl;
  const int sg = s >> 2, sr = s & 3;
  const size_t pb = (((size_t)b*CH_)*H_ + h)*S_ + s;
  float mg = -1e30f;
  float mv[8], lv[8];
#pragma unroll
  for (int k = 0; k < 8; ++k){
    mv[k] = mPart[pb + (size_t)k*128];
    lv[k] = lPart[pb + (size_t)k*128];
    mg = fmaxf(mg, mv[k]);
  }
  const size_t off_s = (size_t)sr*64 + sg*16 + (lane>>2)*256 + (lane&3)*4;
  float L = 0.f, ax0 = 0.f, ax1 = 0.f, ax2 = 0.f, ax3 = 0.f;
#pragma unroll
  for (int k = 0; k < 8; ++k){
    float wgt = __expf(mv[k] - mg);
    L += lv[k]*wgt;
    size_t base3 = ((((size_t)b*CH_ + k)*H_ + h)*S_) * D_;
    float4 a4 = *(const float4*)&axPart[base3 + off_s];
    ax0 += a4.x*wgt; ax1 += a4.y*wgt; ax2 += a4.z*wgt; ax3 += a4.w*wgt;
  }
  float inv = 1.f / L;
  av[sl][lane*4+0] = ax0*inv; av[sl][lane*4+1] = ax1*inv;
  av[sl][lane*4+2] = ax2*inv; av[sl][lane*4+3] = ax3*inv;
  __syncthreads();
  float acc = bv[h*64 + lane];
  for (int d = 0; d < 256; d += 2){
    float2 a2 = *(const float2*)&av[sl][d];
    acc += a2.x * WvT[(size_t)d*512     + h*64 + lane];
    acc += a2.y * WvT[(size_t)(d+1)*512 + h*64 + lane];
  }
  upd[((size_t)b*S_ + s)*DI_ + h*64 + lane] = acc;
}

// ============ post chain (exact R7/R12): wave = 1 row, lane = 1 out col ============
__global__ __launch_bounds__(256) void k_sA(
    const float* __restrict__ upd, const float* __restrict__ WcT,
    const float* __restrict__ bc, float* __restrict__ updc)
{
  __shared__ __align__(16) float act[4][512];
  const int lane = threadIdx.x & 63, w = threadIdx.x >> 6;
  const int row = blockIdx.x*4 + w;
  const int col = blockIdx.y*64 + lane;
  *(float4*)&act[w][lane*8]     = *(const float4*)&upd[(size_t)row*DI_ + lane*8];
  *(float4*)&act[w][lane*8 + 4] = *(const float4*)&upd[(size_t)row*DI_ + lane*8 + 4];
  const float* Wp = WcT + col;
  float acc = 0.f;
#pragma unroll 4
  for (int k4 = 0; k4 < 128; ++k4){
    float4 a = *(const float4*)&act[w][k4*4];
    acc += a.x * Wp[(size_t)(k4*4+0)*256];
    acc += a.y * Wp[(size_t)(k4*4+1)*256];
    acc += a.z * Wp[(size_t)(k4*4+2)*256];
    acc += a.w * Wp[(size_t)(k4*4+3)*256];
  }
  updc[(size_t)row*D_ + col] = acc + bc[col];
}

__global__ __launch_bounds__(256) void k_sB(
    const float* __restrict__ updc, const float* __restrict__ slots,
    const float* __restrict__ wihT, const float* __restrict__ whhT,
    const float* __restrict__ bih, const float* __restrict__ bhh,
    float* __restrict__ snl)
{
  __shared__ __align__(16) float au[4][256];
  __shared__ __align__(16) float as[4][256];
  const int lane = threadIdx.x & 63, w = threadIdx.x >> 6;
  const int row = blockIdx.x*4 + w;
  const int d   = blockIdx.y*64 + lane;
  *(float4*)&au[w][lane*4] = *(const float4*)&updc[(size_t)row*D_ + lane*4];
  *(float4*)&as[w][lane*4] = *(const float4*)&slots[(size_t)row*D_ + lane*4];
  const float* Wi = wihT + d;
  const float* Wh = whhT + d;
  float air=0.f, aiz=0.f, ain=0.f, ahr=0.f, ahz=0.f, ahn=0.f;
#pragma unroll 2
  for (int k4 = 0; k4 < 64; ++k4){
    float4 u = *(const float4*)&au[w][k4*4];
    float4 s = *(const float4*)&as[w][k4*4];
#pragma unroll
    for (int j = 0; j < 4; ++j){
      int k = k4*4 + j;
      float uv = (j==0)?u.x:(j==1)?u.y:(j==2)?u.z:u.w;
      float sv = (j==0)?s.x:(j==1)?s.y:(j==2)?s.z:s.w;
      air += uv * Wi[(size_t)k*768];
      aiz += uv * Wi[(size_t)k*768 + 256];
      ain += uv * Wi[(size_t)k*768 + 512];
      ahr += sv * Wh[(size_t)k*768];
      ahz += sv * Wh[(size_t)k*768 + 256];
      ahn += sv * Wh[(size_t)k*768 + 512];
    }
  }
  float ir = air + bih[d]     + ahr + bhh[d];
  float iz = aiz + bih[256+d] + ahz + bhh[256+d];
  float rg = 1.f/(1.f + __expf(-ir));
  float zg = 1.f/(1.f + __expf(-iz));
  float ng = tanhf(ain + bih[512+d] + rg*(ahn + bhh[512+d]));
  snl[(size_t)row*D_ + d] = (1.f - zg)*ng + zg*as[w][d];
}

__global__ __launch_bounds__(256) void k_sC(
    const float* __restrict__ snl, const float* __restrict__ lfg, const float* __restrict__ lfb,
    const float* __restrict__ W1T, const float* __restrict__ b1, float* __restrict__ h1)
{
  __shared__ __align__(16) float a[4][256];
  const int lane = threadIdx.x & 63, w = threadIdx.x >> 6;
  const int row = blockIdx.x*4 + w;
  const int o   = blockIdx.y*64 + lane;
  float4 v = *(const float4*)&snl[(size_t)row*D_ + lane*4];
  float s = v.x + v.y + v.z + v.w;
  float q = v.x*v.x + v.y*v.y + v.z*v.z + v.w*v.w;
#pragma unroll
  for (int m = 1; m < 64; m <<= 1){ s += __shfl_xor(s, m); q += __shfl_xor(q, m); }
  float mean = s * 0.00390625f;
  float var  = q * 0.00390625f - mean*mean;
  float rs = rsqrtf(var + 1e-5f);
  float4 gv = *(const float4*)&lfg[lane*4];
  float4 bv = *(const float4*)&lfb[lane*4];
  a[w][lane*4+0] = (v.x-mean)*rs*gv.x + bv.x;
  a[w][lane*4+1] = (v.y-mean)*rs*gv.y + bv.y;
  a[w][lane*4+2] = (v.z-mean)*rs*gv.z + bv.z;
  a[w][lane*4+3] = (v.w-mean)*rs*gv.w + bv.w;
  const float* Wp = W1T + o;
  float acc = 0.f;
#pragma unroll 4
  for (int k4 = 0; k4 < 64; ++k4){
    float4 av = *(const float4*)&a[w][k4*4];
    acc += av.x * Wp[(size_t)(k4*4+0)*1024];
    acc += av.y * Wp[(size_t)(k4*4+1)*1024];
    acc += av.z * Wp[(size_t)(k4*4+2)*1024];
    acc += av.w * Wp[(size_t)(k4*4+3)*1024];
  }
  h1[(size_t)row*HID_ + o] = fmaxf(acc + b1[o], 0.f);
}

__global__ __launch_bounds__(256) void k_sD(
    const float* __restrict__ h1, const float* __restrict__ snl,
    const float* __restrict__ W2T, const float* __restrict__ b2, float* __restrict__ dst)
{
  __shared__ __align__(16) float a[4][1024];
  const int lane = threadIdx.x & 63, w = threadIdx.x >> 6;
  const int row = blockIdx.x*4 + w;
  const int o   = blockIdx.y*64 + lane;
#pragma unroll
  for (int j = 0; j < 4; ++j)
    *(float4*)&a[w][lane*16 + j*4] = *(const float4*)&h1[(size_t)row*HID_ + lane*16 + j*4];
  const float* Wp = W2T + o;
  float acc = 0.f;
#pragma unroll 4
  for (int k4 = 0; k4 < 256; ++k4){
    float4 av = *(const float4*)&a[w][k4*4];
    acc += av.x * Wp[(size_t)(k4*4+0)*256];
    acc += av.y * Wp[(size_t)(k4*4+1)*256];
    acc += av.z * Wp[(size_t)(k4*4+2)*256];
    acc += av.w * Wp[(size_t)(k4*4+3)*256];
  }
  dst[(size_t)row*D_ + o] = snl[(size_t)row*D_ + o] + acc + b2[o];
}

extern "C" void kernel_launch(void* const* d_in, const int* in_sizes, int n_in,
                              void* d_out, int out_size, void* d_ws, size_t ws_size,
                              hipStream_t stream)
{
  const float* x       = (const float*)d_in[0];
  const float* noise   = (const float*)d_in[1];
  const float* mu      = (const float*)d_in[2];
  const float* lsig    = (const float*)d_in[3];
  const float* ln_in_g = (const float*)d_in[4];
  const float* ln_in_b = (const float*)d_in[5];
  const float* ln_s_g  = (const float*)d_in[6];
  const float* ln_s_b  = (const float*)d_in[7];
  const float* ln_ff_g = (const float*)d_in[8];
  const float* ln_ff_b = (const float*)d_in[9];
  const float* Wq  = (const float*)d_in[10]; const float* bq  = (const float*)d_in[11];
  const float* Wk  = (const float*)d_in[12]; const float* bk  = (const float*)d_in[13];
  const float* Wv  = (const float*)d_in[14]; const float* bv  = (const float*)d_in[15];
  const float* Wc  = (const float*)d_in[16]; const float* bc  = (const float*)d_in[17];
  const float* wih = (const float*)d_in[18]; const float* whh = (const float*)d_in[19];
  const float* bih = (const float*)d_in[20]; const float* bhh = (const float*)d_in[21];
  const float* W1  = (const float*)d_in[22]; const float* b1  = (const float*)d_in[23];
  const float* W2  = (const float*)d_in[24]; const float* b2  = (const float*)d_in[25];

  char* ws = (char*)d_ws;
  unsigned short* xn  = (unsigned short*)(ws + 0);
  unsigned short* xnT = (unsigned short*)(ws + 67108864);
  float* slots = (float*)(ws + 134217728);
  unsigned short* qp = (unsigned short*)(ws + 134742016);
  float* qb   = (float*)(ws + 136839168);
  float* mP   = (float*)(ws + 136855552);
  float* lP   = (float*)(ws + 136986624);
  float* axP  = (float*)(ws + 137117696);
  float* upd  = (float*)(ws + 170672128);
  float* WqT  = (float*)(ws + 171720704);
  float* WvT  = (float*)(ws + 172244992);
  float* WcT  = (float*)(ws + 172769280);
  float* wihT = (float*)(ws + 173293568);
  float* whhT = (float*)(ws + 174080000);
  float* W1T  = (float*)(ws + 174866432);
  float* W2T  = (float*)(ws + 175915008);
  // overlays inside axP region (dead at their use times):
  float* updc = (float*)(ws + 137117696);
  float* snl  = (float*)(ws + 137641984);
  float* h1   = (float*)(ws + 138166272);
  float* ql   = (float*)(ws + 141000704);   // consumed by preB before flash writes axP

  if (ws_size < (size_t)176963584ull){
    k_badws<<<512, 256, 0, stream>>>((float*)d_out);
    return;
  }

  k_init_slots<<<512, 256, 0, stream>>>(noise, mu, lsig, slots);
  k_ln_x<<<2048, 256, 0, stream>>>(x, ln_in_g, ln_in_b, xn, xnT);
  k_tr_all<<<1280, dim3(32, 8), 0, stream>>>(Wq, Wv, Wc, wih, whh, W1, W2,
                                             WqT, WvT, WcT, wihT, whhT, W1T, W2T);

  for (int it = 0; it < 3; ++it){
    k_preA<<<dim3(128, 8), 256, 0, stream>>>(slots, ln_s_g, ln_s_b, WqT, bq, ql);
    k_preB<<<dim3(256, 4), 256, 0, stream>>>(ql, Wk, bk, qp, qb);
    k_flash<<<dim3(CH_, B_), 512, 0, stream>>>(xn, xnT, qp, qb, mP, lP, axP);
    k_combine<<<1024, 256, 0, stream>>>(mP, lP, axP, WvT, bv, upd);
    k_sA<<<dim3(128, 4),  256, 0, stream>>>(upd, WcT, bc, updc);
    k_sB<<<dim3(128, 4),  256, 0, stream>>>(updc, slots, wihT, whhT, bih, bhh, snl);
    k_sC<<<dim3(128, 16), 256, 0, stream>>>(snl, ln_ff_g, ln_ff_b, W1T, b1, h1);
    k_sD<<<dim3(128, 4),  256, 0, stream>>>(h1, snl, W2T, b2, (it == 2) ? (float*)d_out : slots);
  }
}

// Round 16
// 557.707 us; speedup vs baseline: 1.0577x; 1.0120x over previous
//
#include <hip/hip_runtime.h>
#include <stdint.h>

#define B_   32
#define N_   4096
#define D_   256
#define H_   8
#define S_   16
#define DI_  512
#define HID_ 1024
#define CH_  8
#define NCHUNK_ 512
#define SCALE_ 0.0625f

typedef short  short8 __attribute__((ext_vector_type(8)));
typedef float  f32x4  __attribute__((ext_vector_type(4)));

__device__ __forceinline__ unsigned short f2bf(float x){
  union { float f; unsigned u; } v; v.f = x;
  unsigned r = v.u + 0x7FFFu + ((v.u >> 16) & 1u);
  return (unsigned short)(r >> 16);
}

__device__ __forceinline__ void gld16(const void* g, void* l){
  __builtin_amdgcn_global_load_lds(
      (const __attribute__((address_space(1))) unsigned int*)g,
      (__attribute__((address_space(3))) unsigned int*)l, 16, 0, 0);
}

// ---------------- ws too small sentinel ----------------
__global__ void k_badws(float* out){ out[blockIdx.x*256 + threadIdx.x] = 1e9f; }

// ---------------- slots init ----------------
__global__ __launch_bounds__(256) void k_init_slots(
    const float* __restrict__ noise, const float* __restrict__ mu,
    const float* __restrict__ lsig, float* __restrict__ slots)
{
  int i = blockIdx.x*256 + threadIdx.x;   // < 131072
  int d = i & 255;
  slots[i] = mu[d] + expf(lsig[d]) * noise[i];
}

// ---------------- all 7 weight transposes in ONE launch (proven R10-R12) ----------------
__global__ __launch_bounds__(256) void k_tr_all(
    const float* __restrict__ Wq,  const float* __restrict__ Wv,  const float* __restrict__ Wc,
    const float* __restrict__ wih, const float* __restrict__ whh,
    const float* __restrict__ W1,  const float* __restrict__ W2,
    float* __restrict__ WqT, float* __restrict__ WvT, float* __restrict__ WcT,
    float* __restrict__ wihT, float* __restrict__ whhT,
    float* __restrict__ W1T, float* __restrict__ W2T)
{
  __shared__ float t[32][33];
  const int id = blockIdx.x;
  const float* src; float* dst; int R, C, bx, by;
  if      (id < 128) { src=Wq;  dst=WqT;  R=512;  C=256;  int s=id;      bx=s&7;  by=s>>3; }
  else if (id < 256) { src=Wv;  dst=WvT;  R=512;  C=256;  int s=id-128;  bx=s&7;  by=s>>3; }
  else if (id < 384) { src=Wc;  dst=WcT;  R=256;  C=512;  int s=id-256;  bx=s&15; by=s>>4; }
  else if (id < 576) { src=wih; dst=wihT; R=768;  C=256;  int s=id-384;  bx=s&7;  by=s>>3; }
  else if (id < 768) { src=whh; dst=whhT; R=768;  C=256;  int s=id-576;  bx=s&7;  by=s>>3; }
  else if (id < 1024){ src=W1;  dst=W1T;  R=1024; C=256;  int s=id-768;  bx=s&7;  by=s>>3; }
  else               { src=W2;  dst=W2T;  R=256;  C=1024; int s=id-1024; bx=s&31; by=s>>5; }
  int c0 = bx*32, r0 = by*32;
  int tx = threadIdx.x, ty = threadIdx.y;   // 32 x 8
  for (int j = 0; j < 32; j += 8){
    int r = r0 + ty + j, c = c0 + tx;
    if (r < R && c < C) t[ty+j][tx] = src[(size_t)r*C + c];
  }
  __syncthreads();
  for (int j = 0; j < 32; j += 8){
    int c = c0 + ty + j, r = r0 + tx;
    if (c < C && r < R) dst[(size_t)c*R + r] = t[tx][ty+j];
  }
}

// ---------------- LN(x) -> xn bf16 [B][N][D] and xnT bf16 [B][D][N] ----------------
// R12 structure; unroll pragmas opened (2 / 4) for memory-level parallelism.
__global__ __launch_bounds__(256) void k_ln_x(
    const float* __restrict__ x, const float* __restrict__ g, const float* __restrict__ bb,
    unsigned short* __restrict__ xn, unsigned short* __restrict__ xnT)
{
  __shared__ __align__(16) char tile[32768];   // 64 rows x 256 bf16, swizzled
  const int blk = blockIdx.x;
  const int b  = blk >> 6;
  const int n0 = (blk & 63) * 64;
  const int t = threadIdx.x;
  const int lane = t & 63;
  const int w = t >> 6;
  float4 gv = *(const float4*)&g[lane*4];
  float4 bv = *(const float4*)&bb[lane*4];
#pragma unroll 2
  for (int it = 0; it < 16; ++it){
    const int nl = w*16 + it;
    const size_t row = (size_t)b*N_ + n0 + nl;
    float4 xv = *(const float4*)&x[row*256 + lane*4];
    float s = xv.x + xv.y + xv.z + xv.w;
    float q = xv.x*xv.x + xv.y*xv.y + xv.z*xv.z + xv.w*xv.w;
#pragma unroll
    for (int m = 1; m < 64; m <<= 1){ s += __shfl_xor(s, m); q += __shfl_xor(q, m); }
    float mean = s * 0.00390625f;
    float var  = q * 0.00390625f - mean*mean;
    float rs = rsqrtf(var + 1e-5f);
    unsigned short u0 = f2bf((xv.x-mean)*rs*gv.x + bv.x);
    unsigned short u1 = f2bf((xv.y-mean)*rs*gv.y + bv.y);
    unsigned short u2 = f2bf((xv.z-mean)*rs*gv.z + bv.z);
    unsigned short u3 = f2bf((xv.w-mean)*rs*gv.w + bv.w);
    uint2 pk; pk.x = (unsigned)u0 | ((unsigned)u1 << 16); pk.y = (unsigned)u2 | ((unsigned)u3 << 16);
    *(uint2*)&xn[row*256 + lane*4] = pk;
    *(uint2*)(tile + nl*512 + ((lane*8) ^ ((nl & 7) << 4))) = pk;
  }
  __syncthreads();
#pragma unroll 4
  for (int j = 0; j < 32; ++j){
    int flat = j*256 + t;           // 8192 dwords
    int d  = flat >> 5;             // 0..255
    int np = (flat & 31) * 2;       // n pair base
    unsigned short lo = *(const unsigned short*)(tile + np*512     + ((2*d) ^ ((np     & 7) << 4)));
    unsigned short hi = *(const unsigned short*)(tile + (np+1)*512 + ((2*d) ^ (((np+1) & 7) << 4)));
    *(unsigned*)&xnT[((size_t)b*D_ + d)*N_ + n0 + np] = (unsigned)lo | ((unsigned)hi << 16);
  }
}

// ---------------- preA: LN(slots) + ql = sn @ WqT + bq  (exact R7/R12) ----------------
__global__ __launch_bounds__(256) void k_preA(
    const float* __restrict__ slots, const float* __restrict__ lsg, const float* __restrict__ lsb,
    const float* __restrict__ WqT, const float* __restrict__ bq, float* __restrict__ ql)
{
  __shared__ __align__(16) float a[4][256];
  const int lane = threadIdx.x & 63, w = threadIdx.x >> 6;
  const int row = blockIdx.x*4 + w;            // 0..511
  const int o   = blockIdx.y*64 + lane;        // 0..511
  float4 v = *(const float4*)&slots[(size_t)row*D_ + lane*4];
  float s = v.x + v.y + v.z + v.w;
  float q = v.x*v.x + v.y*v.y + v.z*v.z + v.w*v.w;
#pragma unroll
  for (int m = 1; m < 64; m <<= 1){ s += __shfl_xor(s, m); q += __shfl_xor(q, m); }
  float mean = s * 0.00390625f;
  float var  = q * 0.00390625f - mean*mean;
  float rs = rsqrtf(var + 1e-5f);
  float4 gv = *(const float4*)&lsg[lane*4];
  float4 bv = *(const float4*)&lsb[lane*4];
  a[w][lane*4+0] = (v.x-mean)*rs*gv.x + bv.x;
  a[w][lane*4+1] = (v.y-mean)*rs*gv.y + bv.y;
  a[w][lane*4+2] = (v.z-mean)*rs*gv.z + bv.z;
  a[w][lane*4+3] = (v.w-mean)*rs*gv.w + bv.w;
  const float* Wp = WqT + o;
  float acc = 0.f;
#pragma unroll 4
  for (int k4 = 0; k4 < 64; ++k4){
    float4 av = *(const float4*)&a[w][k4*4];
    acc += av.x * Wp[(size_t)(k4*4+0)*512];
    acc += av.y * Wp[(size_t)(k4*4+1)*512];
    acc += av.z * Wp[(size_t)(k4*4+2)*512];
    acc += av.w * Wp[(size_t)(k4*4+3)*512];
  }
  ql[(size_t)row*DI_ + o] = acc + bq[o];
}

// ---------------- preB: qp = SCALE*(ql_h @ Wk_h), qb = SCALE*(ql_h . bk_h)  (exact R7/R12) ----------------
__global__ __launch_bounds__(256) void k_preB(
    const float* __restrict__ ql, const float* __restrict__ Wk, const float* __restrict__ bk,
    unsigned short* __restrict__ qp, float* __restrict__ qb)
{
  __shared__ __align__(16) float qs[16][64];
  const int id = blockIdx.x;          // 256 = b*8 + h
  const int b  = id >> 3;
  const int h  = id & 7;
  const int cb = blockIdx.y;          // 0..3
  const int c0 = cb*64;
  const int t = threadIdx.x;
  const int lane = t & 63, w = t >> 6;
  {
    int flat = t*4;                   // 1024 floats = 16 rows x 64
    int s = flat >> 6, k = flat & 63;
    *(float4*)&qs[s][k] = *(const float4*)&ql[((size_t)(b*S_ + s))*DI_ + h*64 + k];
  }
  __syncthreads();
  if (cb == 0){
    float bkv = bk[h*64 + lane];
#pragma unroll
    for (int r = 0; r < 4; ++r){
      int s = w*4 + r;
      float v = qs[s][lane] * bkv;
#pragma unroll
      for (int m = 1; m < 64; m <<= 1) v += __shfl_xor(v, m);
      if (lane == 0) qb[((size_t)b*H_ + h)*S_ + s] = v * SCALE_;
    }
  }
  float acc[4] = {};
  const float* Wp = Wk + (size_t)(h*64)*256 + c0 + lane;
#pragma unroll 4
  for (int k = 0; k < 64; ++k){
    float wv = Wp[(size_t)k*256];
    acc[0] += qs[w*4+0][k] * wv;
    acc[1] += qs[w*4+1][k] * wv;
    acc[2] += qs[w*4+2][k] * wv;
    acc[3] += qs[w*4+3][k] * wv;
  }
#pragma unroll
  for (int r = 0; r < 4; ++r){
    int s = w*4 + r;
    qp[(((size_t)b*H_ + h)*S_ + s)*D_ + c0 + lane] = f2bf(SCALE_ * acc[r]);
  }
}

// ---------------- flash (exact R12): single-buffered 80 KB, async gld16, 2 blocks/CU ----------------
__global__ __launch_bounds__(512, 2) void k_flash(
    const unsigned short* __restrict__ xn, const unsigned short* __restrict__ xnT,
    const unsigned short* __restrict__ qp, const float* __restrict__ qb,
    float* __restrict__ mPart, float* __restrict__ lPart, float* __restrict__ axPart)
{
  __shared__ __align__(16) char lds[81920];  // xn 32K | xnT 32K @32768 | P 8x2K @65536
  const int ch = blockIdx.x;
  const int b  = blockIdx.y;
  const int t  = threadIdx.x;
  const int lane = t & 63;
  const int w  = t >> 6;          // wave == head
  const int g  = lane >> 4;       // 0..3
  const int c  = lane & 15;       // 0..15
  const int n0 = ch * NCHUNK_;

  short8 aq[8];
#pragma unroll
  for (int ks = 0; ks < 8; ++ks)
    aq[ks] = *(const short8*)&qp[(((size_t)b*H_ + w)*S_ + c)*D_ + ks*32 + g*8];
  float qbr[4];
#pragma unroll
  for (int r = 0; r < 4; ++r)
    qbr[r] = qb[((size_t)b*H_ + w)*S_ + g*4 + r];

  f32x4 accX[16];
#pragma unroll
  for (int i = 0; i < 16; ++i){ f32x4 z = {0.f,0.f,0.f,0.f}; accX[i] = z; }
  float mrun[4] = {-1e30f,-1e30f,-1e30f,-1e30f};
  float lrun[4] = {0.f,0.f,0.f,0.f};

  auto ISSUE = [&](int tl){
#pragma unroll
    for (int j = 0; j < 4; ++j){           // xn rows: 2 rows per inst
      int rl = w*8 + j*2 + (lane >> 5);
      int cs = (lane & 31) ^ (rl & 7);     // pre-swizzled source chunk
      gld16(&xn[((size_t)b*N_ + n0 + tl*64 + rl)*D_ + cs*8],
            lds + (w*8 + j*2)*512);
    }
#pragma unroll
    for (int j = 0; j < 4; ++j){           // xnT rows: 8 rows per inst
      int dl = w*32 + j*8 + (lane >> 3);
      int cs = (lane & 7) ^ (dl & 7);
      gld16(&xnT[((size_t)b*D_ + dl)*N_ + n0 + tl*64 + cs*8],
            lds + 32768 + (w*32 + j*8)*128);
    }
  };

  ISSUE(0);
#pragma unroll 1
  for (int tl = 0; tl < 8; ++tl){
    __syncthreads();                       // drains vmcnt: tile ready for all waves
    const char* xb  = lds;
    const char* xbT = lds + 32768;
    char* pbuf = lds + 65536 + w*2048;
    f32x4 lg[4];
#pragma unroll
    for (int nf = 0; nf < 4; ++nf){ f32x4 z = {0.f,0.f,0.f,0.f}; lg[nf] = z; }
#pragma unroll
    for (int ks = 0; ks < 8; ++ks){
#pragma unroll
      for (int nf = 0; nf < 4; ++nf){
        int n = nf*16 + c;
        short8 bf = *(const short8*)(xb + n*512 + (((ks*32 + g*8)*2) ^ ((n & 7) << 4)));
        lg[nf] = __builtin_amdgcn_mfma_f32_16x16x32_bf16(aq[ks], bf, lg[nf], 0, 0, 0);
      }
    }
    float tmax[4];
#pragma unroll
    for (int r = 0; r < 4; ++r){
      lg[0][r] += qbr[r]; lg[1][r] += qbr[r]; lg[2][r] += qbr[r]; lg[3][r] += qbr[r];
      tmax[r] = fmaxf(fmaxf(lg[0][r], lg[1][r]), fmaxf(lg[2][r], lg[3][r]));
      tmax[r] = fmaxf(tmax[r], __shfl_xor(tmax[r], 1));
      tmax[r] = fmaxf(tmax[r], __shfl_xor(tmax[r], 2));
      tmax[r] = fmaxf(tmax[r], __shfl_xor(tmax[r], 4));
      tmax[r] = fmaxf(tmax[r], __shfl_xor(tmax[r], 8));
    }
    float fac[4], psum[4];
#pragma unroll
    for (int r = 0; r < 4; ++r){
      float mnew = fmaxf(mrun[r], tmax[r]);
      fac[r] = __expf(mrun[r] - mnew);
      mrun[r] = mnew;
      lrun[r] *= fac[r];
      psum[r] = 0.f;
    }
#pragma unroll
    for (int i = 0; i < 16; ++i){
      accX[i][0] *= fac[0]; accX[i][1] *= fac[1]; accX[i][2] *= fac[2]; accX[i][3] *= fac[3];
    }
#pragma unroll
    for (int nf = 0; nf < 4; ++nf){
#pragma unroll
      for (int r = 0; r < 4; ++r){
        float p = __expf(lg[nf][r] - mrun[r]);
        psum[r] += p;
        int row = g*4 + r;
        *(unsigned short*)(pbuf + row*128 + (((nf*16 + c)*2) ^ ((row & 7) << 4))) = f2bf(p);
      }
    }
#pragma unroll
    for (int r = 0; r < 4; ++r){
      psum[r] += __shfl_xor(psum[r], 1);
      psum[r] += __shfl_xor(psum[r], 2);
      psum[r] += __shfl_xor(psum[r], 4);
      psum[r] += __shfl_xor(psum[r], 8);
      lrun[r] += psum[r];
    }
#pragma unroll
    for (int ks = 0; ks < 2; ++ks){
      short8 pa = *(const short8*)(pbuf + c*128 + (((ks*32 + g*8)*2) ^ ((c & 7) << 4)));
#pragma unroll
      for (int df = 0; df < 16; ++df){
        int d = df*16 + c;
        short8 bt = *(const short8*)(xbT + d*128 + (((ks*32 + g*8)*2) ^ ((d & 7) << 4)));
        accX[df] = __builtin_amdgcn_mfma_f32_16x16x32_bf16(pa, bt, accX[df], 0, 0, 0);
      }
    }
    __syncthreads();                       // all waves done reading tile
    if (tl < 7) ISSUE(tl + 1);             // overwrite with next tile (async)
  }
  size_t base = (((size_t)b*CH_ + ch)*H_ + w)*S_;
  if (c == 0){
#pragma unroll
    for (int r = 0; r < 4; ++r){
      mPart[base + g*4 + r] = mrun[r];
      lPart[base + g*4 + r] = lrun[r];
    }
  }
  size_t base3 = base * D_;
#pragma unroll
  for (int df = 0; df < 16; ++df){
#pragma unroll
    for (int r = 0; r < 4; ++r){
      axPart[base3 + df*256 + r*64 + lane] = accX[df][r];
    }
  }
}

// ---------------- combine chunks + Wv projection -> upd [B][S][DI]  (exact R12) ----------------
__global__ __launch_bounds__(256) void k_combine(
    const float* __restrict__ mPart, const float* __restrict__ lPart, const float* __restrict__ axPart,
    const float* __restrict__ WvT, const float* __restrict__ bv, float* __restrict__ upd)
{
  __shared__ __align__(16) float av[4][256];
  const int id = blockIdx.x;              // 1024 = b*32 + h*4 + sq
  const int b  = id >> 5;
  const int h  = (id >> 2) & 7;
  const int sq = id & 3;
  const int t = threadIdx.x;
  const int sl = t >> 6;
  const int lane = t & 63;
  const int s = sq*4 + sl;
  const int sg = s >> 2, sr = s & 3;
  const size_t pb = (((size_t)b*CH_)*H_ + h)*S_ + s;
  float mg = -1e30f;
  float mv[8], lv[8];
#pragma unroll
  for (int k = 0; k < 8; ++k){
    mv[k] = mPart[pb + (size_t)k*128];
    lv[k] = lPart[pb + (size_t)k*128];
    mg = fmaxf(mg, mv[k]);
  }
  const size_t off_s = (size_t)sr*64 + sg*16 + (lane>>2)*256 + (lane&3)*4;
  float L = 0.f, ax0 = 0.f, ax1 = 0.f, ax2 = 0.f, ax3 = 0.f;
#pragma unroll
  for (int k = 0; k < 8; ++k){
    float wgt = __expf(mv[k] - mg);
    L += lv[k]*wgt;
    size_t base3 = ((((size_t)b*CH_ + k)*H_ + h)*S_) * D_;
    float4 a4 = *(const float4*)&axPart[base3 + off_s];
    ax0 += a4.x*wgt; ax1 += a4.y*wgt; ax2 += a4.z*wgt; ax3 += a4.w*wgt;
  }
  float inv = 1.f / L;
  av[sl][lane*4+0] = ax0*inv; av[sl][lane*4+1] = ax1*inv;
  av[sl][lane*4+2] = ax2*inv; av[sl][lane*4+3] = ax3*inv;
  __syncthreads();
  float acc = bv[h*64 + lane];
  for (int d = 0; d < 256; d += 2){
    float2 a2 = *(const float2*)&av[sl][d];
    acc += a2.x * WvT[(size_t)d*512     + h*64 + lane];
    acc += a2.y * WvT[(size_t)(d+1)*512 + h*64 + lane];
  }
  upd[((size_t)b*S_ + s)*DI_ + h*64 + lane] = acc;
}

// ============ post chain (exact R7/R12): wave = 1 row, lane = 1 out col ============
__global__ __launch_bounds__(256) void k_sA(
    const float* __restrict__ upd, const float* __restrict__ WcT,
    const float* __restrict__ bc, float* __restrict__ updc)
{
  __shared__ __align__(16) float act[4][512];
  const int lane = threadIdx.x & 63, w = threadIdx.x >> 6;
  const int row = blockIdx.x*4 + w;
  const int col = blockIdx.y*64 + lane;
  *(float4*)&act[w][lane*8]     = *(const float4*)&upd[(size_t)row*DI_ + lane*8];
  *(float4*)&act[w][lane*8 + 4] = *(const float4*)&upd[(size_t)row*DI_ + lane*8 + 4];
  const float* Wp = WcT + col;
  float acc = 0.f;
#pragma unroll 4
  for (int k4 = 0; k4 < 128; ++k4){
    float4 a = *(const float4*)&act[w][k4*4];
    acc += a.x * Wp[(size_t)(k4*4+0)*256];
    acc += a.y * Wp[(size_t)(k4*4+1)*256];
    acc += a.z * Wp[(size_t)(k4*4+2)*256];
    acc += a.w * Wp[(size_t)(k4*4+3)*256];
  }
  updc[(size_t)row*D_ + col] = acc + bc[col];
}

__global__ __launch_bounds__(256) void k_sB(
    const float* __restrict__ updc, const float* __restrict__ slots,
    const float* __restrict__ wihT, const float* __restrict__ whhT,
    const float* __restrict__ bih, const float* __restrict__ bhh,
    float* __restrict__ snl)
{
  __shared__ __align__(16) float au[4][256];
  __shared__ __align__(16) float as[4][256];
  const int lane = threadIdx.x & 63, w = threadIdx.x >> 6;
  const int row = blockIdx.x*4 + w;
  const int d   = blockIdx.y*64 + lane;
  *(float4*)&au[w][lane*4] = *(const float4*)&updc[(size_t)row*D_ + lane*4];
  *(float4*)&as[w][lane*4] = *(const float4*)&slots[(size_t)row*D_ + lane*4];
  const float* Wi = wihT + d;
  const float* Wh = whhT + d;
  float air=0.f, aiz=0.f, ain=0.f, ahr=0.f, ahz=0.f, ahn=0.f;
#pragma unroll 2
  for (int k4 = 0; k4 < 64; ++k4){
    float4 u = *(const float4*)&au[w][k4*4];
    float4 s = *(const float4*)&as[w][k4*4];
#pragma unroll
    for (int j = 0; j < 4; ++j){
      int k = k4*4 + j;
      float uv = (j==0)?u.x:(j==1)?u.y:(j==2)?u.z:u.w;
      float sv = (j==0)?s.x:(j==1)?s.y:(j==2)?s.z:s.w;
      air += uv * Wi[(size_t)k*768];
      aiz += uv * Wi[(size_t)k*768 + 256];
      ain += uv * Wi[(size_t)k*768 + 512];
      ahr += sv * Wh[(size_t)k*768];
      ahz += sv * Wh[(size_t)k*768 + 256];
      ahn += sv * Wh[(size_t)k*768 + 512];
    }
  }
  float ir = air + bih[d]     + ahr + bhh[d];
  float iz = aiz + bih[256+d] + ahz + bhh[256+d];
  float rg = 1.f/(1.f + __expf(-ir));
  float zg = 1.f/(1.f + __expf(-iz));
  float ng = tanhf(ain + bih[512+d] + rg*(ahn + bhh[512+d]));
  snl[(size_t)row*D_ + d] = (1.f - zg)*ng + zg*as[w][d];
}

__global__ __launch_bounds__(256) void k_sC(
    const float* __restrict__ snl, const float* __restrict__ lfg, const float* __restrict__ lfb,
    const float* __restrict__ W1T, const float* __restrict__ b1, float* __restrict__ h1)
{
  __shared__ __align__(16) float a[4][256];
  const int lane = threadIdx.x & 63, w = threadIdx.x >> 6;
  const int row = blockIdx.x*4 + w;
  const int o   = blockIdx.y*64 + lane;
  float4 v = *(const float4*)&snl[(size_t)row*D_ + lane*4];
  float s = v.x + v.y + v.z + v.w;
  float q = v.x*v.x + v.y*v.y + v.z*v.z + v.w*v.w;
#pragma unroll
  for (int m = 1; m < 64; m <<= 1){ s += __shfl_xor(s, m); q += __shfl_xor(q, m); }
  float mean = s * 0.00390625f;
  float var  = q * 0.00390625f - mean*mean;
  float rs = rsqrtf(var + 1e-5f);
  float4 gv = *(const float4*)&lfg[lane*4];
  float4 bv = *(const float4*)&lfb[lane*4];
  a[w][lane*4+0] = (v.x-mean)*rs*gv.x + bv.x;
  a[w][lane*4+1] = (v.y-mean)*rs*gv.y + bv.y;
  a[w][lane*4+2] = (v.z-mean)*rs*gv.z + bv.z;
  a[w][lane*4+3] = (v.w-mean)*rs*gv.w + bv.w;
  const float* Wp = W1T + o;
  float acc = 0.f;
#pragma unroll 4
  for (int k4 = 0; k4 < 64; ++k4){
    float4 av = *(const float4*)&a[w][k4*4];
    acc += av.x * Wp[(size_t)(k4*4+0)*1024];
    acc += av.y * Wp[(size_t)(k4*4+1)*1024];
    acc += av.z * Wp[(size_t)(k4*4+2)*1024];
    acc += av.w * Wp[(size_t)(k4*4+3)*1024];
  }
  h1[(size_t)row*HID_ + o] = fmaxf(acc + b1[o], 0.f);
}

__global__ __launch_bounds__(256) void k_sD(
    const float* __restrict__ h1, const float* __restrict__ snl,
    const float* __restrict__ W2T, const float* __restrict__ b2, float* __restrict__ dst)
{
  __shared__ __align__(16) float a[4][1024];
  const int lane = threadIdx.x & 63, w = threadIdx.x >> 6;
  const int row = blockIdx.x*4 + w;
  const int o   = blockIdx.y*64 + lane;
#pragma unroll
  for (int j = 0; j < 4; ++j)
    *(float4*)&a[w][lane*16 + j*4] = *(const float4*)&h1[(size_t)row*HID_ + lane*16 + j*4];
  const float* Wp = W2T + o;
  float acc = 0.f;
#pragma unroll 4
  for (int k4 = 0; k4 < 256; ++k4){
    float4 av = *(const float4*)&a[w][k4*4];
    acc += av.x * Wp[(size_t)(k4*4+0)*256];
    acc += av.y * Wp[(size_t)(k4*4+1)*256];
    acc += av.z * Wp[(size_t)(k4*4+2)*256];
    acc += av.w * Wp[(size_t)(k4*4+3)*256];
  }
  dst[(size_t)row*D_ + o] = snl[(size_t)row*D_ + o] + acc + b2[o];
}

extern "C" void kernel_launch(void* const* d_in, const int* in_sizes, int n_in,
                              void* d_out, int out_size, void* d_ws, size_t ws_size,
                              hipStream_t stream)
{
  const float* x       = (const float*)d_in[0];
  const float* noise   = (const float*)d_in[1];
  const float* mu      = (const float*)d_in[2];
  const float* lsig    = (const float*)d_in[3];
  const float* ln_in_g = (const float*)d_in[4];
  const float* ln_in_b = (const float*)d_in[5];
  const float* ln_s_g  = (const float*)d_in[6];
  const float* ln_s_b  = (const float*)d_in[7];
  const float* ln_ff_g = (const float*)d_in[8];
  const float* ln_ff_b = (const float*)d_in[9];
  const float* Wq  = (const float*)d_in[10]; const float* bq  = (const float*)d_in[11];
  const float* Wk  = (const float*)d_in[12]; const float* bk  = (const float*)d_in[13];
  const float* Wv  = (const float*)d_in[14]; const float* bv  = (const float*)d_in[15];
  const float* Wc  = (const float*)d_in[16]; const float* bc  = (const float*)d_in[17];
  const float* wih = (const float*)d_in[18]; const float* whh = (const float*)d_in[19];
  const float* bih = (const float*)d_in[20]; const float* bhh = (const float*)d_in[21];
  const float* W1  = (const float*)d_in[22]; const float* b1  = (const float*)d_in[23];
  const float* W2  = (const float*)d_in[24]; const float* b2  = (const float*)d_in[25];

  char* ws = (char*)d_ws;
  unsigned short* xn  = (unsigned short*)(ws + 0);
  unsigned short* xnT = (unsigned short*)(ws + 67108864);
  float* slots = (float*)(ws + 134217728);
  unsigned short* qp = (unsigned short*)(ws + 134742016);
  float* qb   = (float*)(ws + 136839168);
  float* mP   = (float*)(ws + 136855552);
  float* lP   = (float*)(ws + 136986624);
  float* axP  = (float*)(ws + 137117696);
  float* upd  = (float*)(ws + 170672128);
  float* WqT  = (float*)(ws + 171720704);
  float* WvT  = (float*)(ws + 172244992);
  float* WcT  = (float*)(ws + 172769280);
  float* wihT = (float*)(ws + 173293568);
  float* whhT = (float*)(ws + 174080000);
  float* W1T  = (float*)(ws + 174866432);
  float* W2T  = (float*)(ws + 175915008);
  // overlays inside axP region (dead at their use times):
  float* updc = (float*)(ws + 137117696);
  float* snl  = (float*)(ws + 137641984);
  float* h1   = (float*)(ws + 138166272);
  float* ql   = (float*)(ws + 141000704);   // consumed by preB before flash writes axP

  if (ws_size < (size_t)176963584ull){
    k_badws<<<512, 256, 0, stream>>>((float*)d_out);
    return;
  }

  k_init_slots<<<512, 256, 0, stream>>>(noise, mu, lsig, slots);
  k_ln_x<<<2048, 256, 0, stream>>>(x, ln_in_g, ln_in_b, xn, xnT);
  k_tr_all<<<1280, dim3(32, 8), 0, stream>>>(Wq, Wv, Wc, wih, whh, W1, W2,
                                             WqT, WvT, WcT, wihT, whhT, W1T, W2T);

  for (int it = 0; it < 3; ++it){
    k_preA<<<dim3(128, 8), 256, 0, stream>>>(slots, ln_s_g, ln_s_b, WqT, bq, ql);
    k_preB<<<dim3(256, 4), 256, 0, stream>>>(ql, Wk, bk, qp, qb);
    k_flash<<<dim3(CH_, B_), 512, 0, stream>>>(xn, xnT, qp, qb, mP, lP, axP);
    k_combine<<<1024, 256, 0, stream>>>(mP, lP, axP, WvT, bv, upd);
    k_sA<<<dim3(128, 4),  256, 0, stream>>>(upd, WcT, bc, updc);
    k_sB<<<dim3(128, 4),  256, 0, stream>>>(updc, slots, wihT, whhT, bih, bhh, snl);
    k_sC<<<dim3(128, 16), 256, 0, stream>>>(snl, ln_ff_g, ln_ff_b, W1T, b1, h1);
    k_sD<<<dim3(128, 4),  256, 0, stream>>>(h1, snl, W2T, b2, (it == 2) ? (float*)d_out : slots);
  }
}

// Round 17
// 556.503 us; speedup vs baseline: 1.0600x; 1.0022x over previous
//
#include <hip/hip_runtime.h>
#include <stdint.h>

#define B_   32
#define N_   4096
#define D_   256
#define H_   8
#define S_   16
#define DI_  512
#define HID_ 1024
#define CH_  8
#define NCHUNK_ 512
#define SCALE_ 0.0625f

typedef short  short8 __attribute__((ext_vector_type(8)));
typedef float  f32x4  __attribute__((ext_vector_type(4)));

__device__ __forceinline__ unsigned short f2bf(float x){
  union { float f; unsigned u; } v; v.f = x;
  unsigned r = v.u + 0x7FFFu + ((v.u >> 16) & 1u);
  return (unsigned short)(r >> 16);
}

__device__ __forceinline__ void gld16(const void* g, void* l){
  __builtin_amdgcn_global_load_lds(
      (const __attribute__((address_space(1))) unsigned int*)g,
      (__attribute__((address_space(3))) unsigned int*)l, 16, 0, 0);
}

// ---------------- ws too small sentinel ----------------
__global__ void k_badws(float* out){ out[blockIdx.x*256 + threadIdx.x] = 1e9f; }

// ---------------- slots init ----------------
__global__ __launch_bounds__(256) void k_init_slots(
    const float* __restrict__ noise, const float* __restrict__ mu,
    const float* __restrict__ lsig, float* __restrict__ slots)
{
  int i = blockIdx.x*256 + threadIdx.x;   // < 131072
  int d = i & 255;
  slots[i] = mu[d] + expf(lsig[d]) * noise[i];
}

// ---------------- all 7 weight transposes in ONE launch (proven R10-R16) ----------------
__global__ __launch_bounds__(256) void k_tr_all(
    const float* __restrict__ Wq,  const float* __restrict__ Wv,  const float* __restrict__ Wc,
    const float* __restrict__ wih, const float* __restrict__ whh,
    const float* __restrict__ W1,  const float* __restrict__ W2,
    float* __restrict__ WqT, float* __restrict__ WvT, float* __restrict__ WcT,
    float* __restrict__ wihT, float* __restrict__ whhT,
    float* __restrict__ W1T, float* __restrict__ W2T)
{
  __shared__ float t[32][33];
  const int id = blockIdx.x;
  const float* src; float* dst; int R, C, bx, by;
  if      (id < 128) { src=Wq;  dst=WqT;  R=512;  C=256;  int s=id;      bx=s&7;  by=s>>3; }
  else if (id < 256) { src=Wv;  dst=WvT;  R=512;  C=256;  int s=id-128;  bx=s&7;  by=s>>3; }
  else if (id < 384) { src=Wc;  dst=WcT;  R=256;  C=512;  int s=id-256;  bx=s&15; by=s>>4; }
  else if (id < 576) { src=wih; dst=wihT; R=768;  C=256;  int s=id-384;  bx=s&7;  by=s>>3; }
  else if (id < 768) { src=whh; dst=whhT; R=768;  C=256;  int s=id-576;  bx=s&7;  by=s>>3; }
  else if (id < 1024){ src=W1;  dst=W1T;  R=1024; C=256;  int s=id-768;  bx=s&7;  by=s>>3; }
  else               { src=W2;  dst=W2T;  R=256;  C=1024; int s=id-1024; bx=s&31; by=s>>5; }
  int c0 = bx*32, r0 = by*32;
  int tx = threadIdx.x, ty = threadIdx.y;   // 32 x 8
  for (int j = 0; j < 32; j += 8){
    int r = r0 + ty + j, c = c0 + tx;
    if (r < R && c < C) t[ty+j][tx] = src[(size_t)r*C + c];
  }
  __syncthreads();
  for (int j = 0; j < 32; j += 8){
    int c = c0 + ty + j, r = r0 + tx;
    if (c < C && r < R) dst[(size_t)c*R + r] = t[tx][ty+j];
  }
}

// ---------------- LN(x) -> xn bf16 [B][N][D] and xnT bf16 [B][D][N] ----------------
// R12 structure; phase 1 loads hoisted into a register array (16 deep MLP).
__global__ __launch_bounds__(256) void k_ln_x(
    const float* __restrict__ x, const float* __restrict__ g, const float* __restrict__ bb,
    unsigned short* __restrict__ xn, unsigned short* __restrict__ xnT)
{
  __shared__ __align__(16) char tile[32768];   // 64 rows x 256 bf16, swizzled
  const int blk = blockIdx.x;
  const int b  = blk >> 6;
  const int n0 = (blk & 63) * 64;
  const int t = threadIdx.x;
  const int lane = t & 63;
  const int w = t >> 6;
  float4 gv = *(const float4*)&g[lane*4];
  float4 bv = *(const float4*)&bb[lane*4];
  // ---- phase 0: issue ALL 16 row loads (fully unrolled, static indices -> registers) ----
  float4 xv[16];
#pragma unroll
  for (int it = 0; it < 16; ++it){
    const int nl = w*16 + it;
    xv[it] = *(const float4*)&x[((size_t)b*N_ + n0 + nl)*256 + lane*4];
  }
  // ---- phase 1: LN + pack + store (loads already in flight/landed) ----
#pragma unroll
  for (int it = 0; it < 16; ++it){
    const int nl = w*16 + it;
    const size_t row = (size_t)b*N_ + n0 + nl;
    float4 v = xv[it];
    float s = v.x + v.y + v.z + v.w;
    float q = v.x*v.x + v.y*v.y + v.z*v.z + v.w*v.w;
#pragma unroll
    for (int m = 1; m < 64; m <<= 1){ s += __shfl_xor(s, m); q += __shfl_xor(q, m); }
    float mean = s * 0.00390625f;
    float var  = q * 0.00390625f - mean*mean;
    float rs = rsqrtf(var + 1e-5f);
    unsigned short u0 = f2bf((v.x-mean)*rs*gv.x + bv.x);
    unsigned short u1 = f2bf((v.y-mean)*rs*gv.y + bv.y);
    unsigned short u2 = f2bf((v.z-mean)*rs*gv.z + bv.z);
    unsigned short u3 = f2bf((v.w-mean)*rs*gv.w + bv.w);
    uint2 pk; pk.x = (unsigned)u0 | ((unsigned)u1 << 16); pk.y = (unsigned)u2 | ((unsigned)u3 << 16);
    *(uint2*)&xn[row*256 + lane*4] = pk;
    *(uint2*)(tile + nl*512 + ((lane*8) ^ ((nl & 7) << 4))) = pk;
  }
  __syncthreads();
#pragma unroll 1
  for (int j = 0; j < 32; ++j){
    int flat = j*256 + t;           // 8192 dwords
    int d  = flat >> 5;             // 0..255
    int np = (flat & 31) * 2;       // n pair base
    unsigned short lo = *(const unsigned short*)(tile + np*512     + ((2*d) ^ ((np     & 7) << 4)));
    unsigned short hi = *(const unsigned short*)(tile + (np+1)*512 + ((2*d) ^ (((np+1) & 7) << 4)));
    *(unsigned*)&xnT[((size_t)b*D_ + d)*N_ + n0 + np] = (unsigned)lo | ((unsigned)hi << 16);
  }
}

// ---------------- preA: LN(slots) + ql = sn @ WqT + bq  (exact R7/R12) ----------------
__global__ __launch_bounds__(256) void k_preA(
    const float* __restrict__ slots, const float* __restrict__ lsg, const float* __restrict__ lsb,
    const float* __restrict__ WqT, const float* __restrict__ bq, float* __restrict__ ql)
{
  __shared__ __align__(16) float a[4][256];
  const int lane = threadIdx.x & 63, w = threadIdx.x >> 6;
  const int row = blockIdx.x*4 + w;            // 0..511
  const int o   = blockIdx.y*64 + lane;        // 0..511
  float4 v = *(const float4*)&slots[(size_t)row*D_ + lane*4];
  float s = v.x + v.y + v.z + v.w;
  float q = v.x*v.x + v.y*v.y + v.z*v.z + v.w*v.w;
#pragma unroll
  for (int m = 1; m < 64; m <<= 1){ s += __shfl_xor(s, m); q += __shfl_xor(q, m); }
  float mean = s * 0.00390625f;
  float var  = q * 0.00390625f - mean*mean;
  float rs = rsqrtf(var + 1e-5f);
  float4 gv = *(const float4*)&lsg[lane*4];
  float4 bv = *(const float4*)&lsb[lane*4];
  a[w][lane*4+0] = (v.x-mean)*rs*gv.x + bv.x;
  a[w][lane*4+1] = (v.y-mean)*rs*gv.y + bv.y;
  a[w][lane*4+2] = (v.z-mean)*rs*gv.z + bv.z;
  a[w][lane*4+3] = (v.w-mean)*rs*gv.w + bv.w;
  const float* Wp = WqT + o;
  float acc = 0.f;
#pragma unroll 4
  for (int k4 = 0; k4 < 64; ++k4){
    float4 av = *(const float4*)&a[w][k4*4];
    acc += av.x * Wp[(size_t)(k4*4+0)*512];
    acc += av.y * Wp[(size_t)(k4*4+1)*512];
    acc += av.z * Wp[(size_t)(k4*4+2)*512];
    acc += av.w * Wp[(size_t)(k4*4+3)*512];
  }
  ql[(size_t)row*DI_ + o] = acc + bq[o];
}

// ---------------- preB: qp = SCALE*(ql_h @ Wk_h), qb = SCALE*(ql_h . bk_h)  (exact R7/R12) ----------------
__global__ __launch_bounds__(256) void k_preB(
    const float* __restrict__ ql, const float* __restrict__ Wk, const float* __restrict__ bk,
    unsigned short* __restrict__ qp, float* __restrict__ qb)
{
  __shared__ __align__(16) float qs[16][64];
  const int id = blockIdx.x;          // 256 = b*8 + h
  const int b  = id >> 3;
  const int h  = id & 7;
  const int cb = blockIdx.y;          // 0..3
  const int c0 = cb*64;
  const int t = threadIdx.x;
  const int lane = t & 63, w = t >> 6;
  {
    int flat = t*4;                   // 1024 floats = 16 rows x 64
    int s = flat >> 6, k = flat & 63;
    *(float4*)&qs[s][k] = *(const float4*)&ql[((size_t)(b*S_ + s))*DI_ + h*64 + k];
  }
  __syncthreads();
  if (cb == 0){
    float bkv = bk[h*64 + lane];
#pragma unroll
    for (int r = 0; r < 4; ++r){
      int s = w*4 + r;
      float v = qs[s][lane] * bkv;
#pragma unroll
      for (int m = 1; m < 64; m <<= 1) v += __shfl_xor(v, m);
      if (lane == 0) qb[((size_t)b*H_ + h)*S_ + s] = v * SCALE_;
    }
  }
  float acc[4] = {};
  const float* Wp = Wk + (size_t)(h*64)*256 + c0 + lane;
#pragma unroll 4
  for (int k = 0; k < 64; ++k){
    float wv = Wp[(size_t)k*256];
    acc[0] += qs[w*4+0][k] * wv;
    acc[1] += qs[w*4+1][k] * wv;
    acc[2] += qs[w*4+2][k] * wv;
    acc[3] += qs[w*4+3][k] * wv;
  }
#pragma unroll
  for (int r = 0; r < 4; ++r){
    int s = w*4 + r;
    qp[(((size_t)b*H_ + h)*S_ + s)*D_ + c0 + lane] = f2bf(SCALE_ * acc[r]);
  }
}

// ---------------- flash (exact R12): single-buffered 80 KB, async gld16 ----------------
__global__ __launch_bounds__(512, 2) void k_flash(
    const unsigned short* __restrict__ xn, const unsigned short* __restrict__ xnT,
    const unsigned short* __restrict__ qp, const float* __restrict__ qb,
    float* __restrict__ mPart, float* __restrict__ lPart, float* __restrict__ axPart)
{
  __shared__ __align__(16) char lds[81920];  // xn 32K | xnT 32K @32768 | P 8x2K @65536
  const int ch = blockIdx.x;
  const int b  = blockIdx.y;
  const int t  = threadIdx.x;
  const int lane = t & 63;
  const int w  = t >> 6;          // wave == head
  const int g  = lane >> 4;       // 0..3
  const int c  = lane & 15;       // 0..15
  const int n0 = ch * NCHUNK_;

  short8 aq[8];
#pragma unroll
  for (int ks = 0; ks < 8; ++ks)
    aq[ks] = *(const short8*)&qp[(((size_t)b*H_ + w)*S_ + c)*D_ + ks*32 + g*8];
  float qbr[4];
#pragma unroll
  for (int r = 0; r < 4; ++r)
    qbr[r] = qb[((size_t)b*H_ + w)*S_ + g*4 + r];

  f32x4 accX[16];
#pragma unroll
  for (int i = 0; i < 16; ++i){ f32x4 z = {0.f,0.f,0.f,0.f}; accX[i] = z; }
  float mrun[4] = {-1e30f,-1e30f,-1e30f,-1e30f};
  float lrun[4] = {0.f,0.f,0.f,0.f};

  auto ISSUE = [&](int tl){
#pragma unroll
    for (int j = 0; j < 4; ++j){           // xn rows: 2 rows per inst
      int rl = w*8 + j*2 + (lane >> 5);
      int cs = (lane & 31) ^ (rl & 7);     // pre-swizzled source chunk
      gld16(&xn[((size_t)b*N_ + n0 + tl*64 + rl)*D_ + cs*8],
            lds + (w*8 + j*2)*512);
    }
#pragma unroll
    for (int j = 0; j < 4; ++j){           // xnT rows: 8 rows per inst
      int dl = w*32 + j*8 + (lane >> 3);
      int cs = (lane & 7) ^ (dl & 7);
      gld16(&xnT[((size_t)b*D_ + dl)*N_ + n0 + tl*64 + cs*8],
            lds + 32768 + (w*32 + j*8)*128);
    }
  };

  ISSUE(0);
#pragma unroll 1
  for (int tl = 0; tl < 8; ++tl){
    __syncthreads();                       // drains vmcnt: tile ready for all waves
    const char* xb  = lds;
    const char* xbT = lds + 32768;
    char* pbuf = lds + 65536 + w*2048;
    f32x4 lg[4];
#pragma unroll
    for (int nf = 0; nf < 4; ++nf){ f32x4 z = {0.f,0.f,0.f,0.f}; lg[nf] = z; }
#pragma unroll
    for (int ks = 0; ks < 8; ++ks){
#pragma unroll
      for (int nf = 0; nf < 4; ++nf){
        int n = nf*16 + c;
        short8 bf = *(const short8*)(xb + n*512 + (((ks*32 + g*8)*2) ^ ((n & 7) << 4)));
        lg[nf] = __builtin_amdgcn_mfma_f32_16x16x32_bf16(aq[ks], bf, lg[nf], 0, 0, 0);
      }
    }
    float tmax[4];
#pragma unroll
    for (int r = 0; r < 4; ++r){
      lg[0][r] += qbr[r]; lg[1][r] += qbr[r]; lg[2][r] += qbr[r]; lg[3][r] += qbr[r];
      tmax[r] = fmaxf(fmaxf(lg[0][r], lg[1][r]), fmaxf(lg[2][r], lg[3][r]));
      tmax[r] = fmaxf(tmax[r], __shfl_xor(tmax[r], 1));
      tmax[r] = fmaxf(tmax[r], __shfl_xor(tmax[r], 2));
      tmax[r] = fmaxf(tmax[r], __shfl_xor(tmax[r], 4));
      tmax[r] = fmaxf(tmax[r], __shfl_xor(tmax[r], 8));
    }
    float fac[4], psum[4];
#pragma unroll
    for (int r = 0; r < 4; ++r){
      float mnew = fmaxf(mrun[r], tmax[r]);
      fac[r] = __expf(mrun[r] - mnew);
      mrun[r] = mnew;
      lrun[r] *= fac[r];
      psum[r] = 0.f;
    }
#pragma unroll
    for (int i = 0; i < 16; ++i){
      accX[i][0] *= fac[0]; accX[i][1] *= fac[1]; accX[i][2] *= fac[2]; accX[i][3] *= fac[3];
    }
#pragma unroll
    for (int nf = 0; nf < 4; ++nf){
#pragma unroll
      for (int r = 0; r < 4; ++r){
        float p = __expf(lg[nf][r] - mrun[r]);
        psum[r] += p;
        int row = g*4 + r;
        *(unsigned short*)(pbuf + row*128 + (((nf*16 + c)*2) ^ ((row & 7) << 4))) = f2bf(p);
      }
    }
#pragma unroll
    for (int r = 0; r < 4; ++r){
      psum[r] += __shfl_xor(psum[r], 1);
      psum[r] += __shfl_xor(psum[r], 2);
      psum[r] += __shfl_xor(psum[r], 4);
      psum[r] += __shfl_xor(psum[r], 8);
      lrun[r] += psum[r];
    }
#pragma unroll
    for (int ks = 0; ks < 2; ++ks){
      short8 pa = *(const short8*)(pbuf + c*128 + (((ks*32 + g*8)*2) ^ ((c & 7) << 4)));
#pragma unroll
      for (int df = 0; df < 16; ++df){
        int d = df*16 + c;
        short8 bt = *(const short8*)(xbT + d*128 + (((ks*32 + g*8)*2) ^ ((d & 7) << 4)));
        accX[df] = __builtin_amdgcn_mfma_f32_16x16x32_bf16(pa, bt, accX[df], 0, 0, 0);
      }
    }
    __syncthreads();                       // all waves done reading tile
    if (tl < 7) ISSUE(tl + 1);             // overwrite with next tile (async)
  }
  size_t base = (((size_t)b*CH_ + ch)*H_ + w)*S_;
  if (c == 0){
#pragma unroll
    for (int r = 0; r < 4; ++r){
      mPart[base + g*4 + r] = mrun[r];
      lPart[base + g*4 + r] = lrun[r];
    }
  }
  size_t base3 = base * D_;
#pragma unroll
  for (int df = 0; df < 16; ++df){
#pragma unroll
    for (int r = 0; r < 4; ++r){
      axPart[base3 + df*256 + r*64 + lane] = accX[df][r];
    }
  }
}

// ---------------- combine chunks + Wv projection -> upd [B][S][DI]  (exact R12) ----------------
__global__ __launch_bounds__(256) void k_combine(
    const float* __restrict__ mPart, const float* __restrict__ lPart, const float* __restrict__ axPart,
    const float* __restrict__ WvT, const float* __restrict__ bv, float* __restrict__ upd)
{
  __shared__ __align__(16) float av[4][256];
  const int id = blockIdx.x;              // 1024 = b*32 + h*4 + sq
  const int b  = id >> 5;
  const int h  = (id >> 2) & 7;
  const int sq = id & 3;
  const int t = threadIdx.x;
  const int sl = t >> 6;
  const int lane = t & 63;
  const int s = sq*4 + sl;
  const int sg = s >> 2, sr = s & 3;
  const size_t pb = (((size_t)b*CH_)*H_ + h)*S_ + s;
  float mg = -1e30f;
  float mv[8], lv[8];
#pragma unroll
  for (int k = 0; k < 8; ++k){
    mv[k] = mPart[pb + (size_t)k*128];
    lv[k] = lPart[pb + (size_t)k*128];
    mg = fmaxf(mg, mv[k]);
  }
  const size_t off_s = (size_t)sr*64 + sg*16 + (lane>>2)*256 + (lane&3)*4;
  float L = 0.f, ax0 = 0.f, ax1 = 0.f, ax2 = 0.f, ax3 = 0.f;
#pragma unroll
  for (int k = 0; k < 8; ++k){
    float wgt = __expf(mv[k] - mg);
    L += lv[k]*wgt;
    size_t base3 = ((((size_t)b*CH_ + k)*H_ + h)*S_) * D_;
    float4 a4 = *(const float4*)&axPart[base3 + off_s];
    ax0 += a4.x*wgt; ax1 += a4.y*wgt; ax2 += a4.z*wgt; ax3 += a4.w*wgt;
  }
  float inv = 1.f / L;
  av[sl][lane*4+0] = ax0*inv; av[sl][lane*4+1] = ax1*inv;
  av[sl][lane*4+2] = ax2*inv; av[sl][lane*4+3] = ax3*inv;
  __syncthreads();
  float acc = bv[h*64 + lane];
  for (int d = 0; d < 256; d += 2){
    float2 a2 = *(const float2*)&av[sl][d];
    acc += a2.x * WvT[(size_t)d*512     + h*64 + lane];
    acc += a2.y * WvT[(size_t)(d+1)*512 + h*64 + lane];
  }
  upd[((size_t)b*S_ + s)*DI_ + h*64 + lane] = acc;
}

// ============ post chain (exact R7/R12): wave = 1 row, lane = 1 out col ============
__global__ __launch_bounds__(256) void k_sA(
    const float* __restrict__ upd, const float* __restrict__ WcT,
    const float* __restrict__ bc, float* __restrict__ updc)
{
  __shared__ __align__(16) float act[4][512];
  const int lane = threadIdx.x & 63, w = threadIdx.x >> 6;
  const int row = blockIdx.x*4 + w;
  const int col = blockIdx.y*64 + lane;
  *(float4*)&act[w][lane*8]     = *(const float4*)&upd[(size_t)row*DI_ + lane*8];
  *(float4*)&act[w][lane*8 + 4] = *(const float4*)&upd[(size_t)row*DI_ + lane*8 + 4];
  const float* Wp = WcT + col;
  float acc = 0.f;
#pragma unroll 4
  for (int k4 = 0; k4 < 128; ++k4){
    float4 a = *(const float4*)&act[w][k4*4];
    acc += a.x * Wp[(size_t)(k4*4+0)*256];
    acc += a.y * Wp[(size_t)(k4*4+1)*256];
    acc += a.z * Wp[(size_t)(k4*4+2)*256];
    acc += a.w * Wp[(size_t)(k4*4+3)*256];
  }
  updc[(size_t)row*D_ + col] = acc + bc[col];
}

__global__ __launch_bounds__(256) void k_sB(
    const float* __restrict__ updc, const float* __restrict__ slots,
    const float* __restrict__ wihT, const float* __restrict__ whhT,
    const float* __restrict__ bih, const float* __restrict__ bhh,
    float* __restrict__ snl)
{
  __shared__ __align__(16) float au[4][256];
  __shared__ __align__(16) float as[4][256];
  const int lane = threadIdx.x & 63, w = threadIdx.x >> 6;
  const int row = blockIdx.x*4 + w;
  const int d   = blockIdx.y*64 + lane;
  *(float4*)&au[w][lane*4] = *(const float4*)&updc[(size_t)row*D_ + lane*4];
  *(float4*)&as[w][lane*4] = *(const float4*)&slots[(size_t)row*D_ + lane*4];
  const float* Wi = wihT + d;
  const float* Wh = whhT + d;
  float air=0.f, aiz=0.f, ain=0.f, ahr=0.f, ahz=0.f, ahn=0.f;
#pragma unroll 2
  for (int k4 = 0; k4 < 64; ++k4){
    float4 u = *(const float4*)&au[w][k4*4];
    float4 s = *(const float4*)&as[w][k4*4];
#pragma unroll
    for (int j = 0; j < 4; ++j){
      int k = k4*4 + j;
      float uv = (j==0)?u.x:(j==1)?u.y:(j==2)?u.z:u.w;
      float sv = (j==0)?s.x:(j==1)?s.y:(j==2)?s.z:s.w;
      air += uv * Wi[(size_t)k*768];
      aiz += uv * Wi[(size_t)k*768 + 256];
      ain += uv * Wi[(size_t)k*768 + 512];
      ahr += sv * Wh[(size_t)k*768];
      ahz += sv * Wh[(size_t)k*768 + 256];
      ahn += sv * Wh[(size_t)k*768 + 512];
    }
  }
  float ir = air + bih[d]     + ahr + bhh[d];
  float iz = aiz + bih[256+d] + ahz + bhh[256+d];
  float rg = 1.f/(1.f + __expf(-ir));
  float zg = 1.f/(1.f + __expf(-iz));
  float ng = tanhf(ain + bih[512+d] + rg*(ahn + bhh[512+d]));
  snl[(size_t)row*D_ + d] = (1.f - zg)*ng + zg*as[w][d];
}

__global__ __launch_bounds__(256) void k_sC(
    const float* __restrict__ snl, const float* __restrict__ lfg, const float* __restrict__ lfb,
    const float* __restrict__ W1T, const float* __restrict__ b1, float* __restrict__ h1)
{
  __shared__ __align__(16) float a[4][256];
  const int lane = threadIdx.x & 63, w = threadIdx.x >> 6;
  const int row = blockIdx.x*4 + w;
  const int o   = blockIdx.y*64 + lane;
  float4 v = *(const float4*)&snl[(size_t)row*D_ + lane*4];
  float s = v.x + v.y + v.z + v.w;
  float q = v.x*v.x + v.y*v.y + v.z*v.z + v.w*v.w;
#pragma unroll
  for (int m = 1; m < 64; m <<= 1){ s += __shfl_xor(s, m); q += __shfl_xor(q, m); }
  float mean = s * 0.00390625f;
  float var  = q * 0.00390625f - mean*mean;
  float rs = rsqrtf(var + 1e-5f);
  float4 gv = *(const float4*)&lfg[lane*4];
  float4 bv = *(const float4*)&lfb[lane*4];
  a[w][lane*4+0] = (v.x-mean)*rs*gv.x + bv.x;
  a[w][lane*4+1] = (v.y-mean)*rs*gv.y + bv.y;
  a[w][lane*4+2] = (v.z-mean)*rs*gv.z + bv.z;
  a[w][lane*4+3] = (v.w-mean)*rs*gv.w + bv.w;
  const float* Wp = W1T + o;
  float acc = 0.f;
#pragma unroll 4
  for (int k4 = 0; k4 < 64; ++k4){
    float4 av = *(const float4*)&a[w][k4*4];
    acc += av.x * Wp[(size_t)(k4*4+0)*1024];
    acc += av.y * Wp[(size_t)(k4*4+1)*1024];
    acc += av.z * Wp[(size_t)(k4*4+2)*1024];
    acc += av.w * Wp[(size_t)(k4*4+3)*1024];
  }
  h1[(size_t)row*HID_ + o] = fmaxf(acc + b1[o], 0.f);
}

__global__ __launch_bounds__(256) void k_sD(
    const float* __restrict__ h1, const float* __restrict__ snl,
    const float* __restrict__ W2T, const float* __restrict__ b2, float* __restrict__ dst)
{
  __shared__ __align__(16) float a[4][1024];
  const int lane = threadIdx.x & 63, w = threadIdx.x >> 6;
  const int row = blockIdx.x*4 + w;
  const int o   = blockIdx.y*64 + lane;
#pragma unroll
  for (int j = 0; j < 4; ++j)
    *(float4*)&a[w][lane*16 + j*4] = *(const float4*)&h1[(size_t)row*HID_ + lane*16 + j*4];
  const float* Wp = W2T + o;
  float acc = 0.f;
#pragma unroll 4
  for (int k4 = 0; k4 < 256; ++k4){
    float4 av = *(const float4*)&a[w][k4*4];
    acc += av.x * Wp[(size_t)(k4*4+0)*256];
    acc += av.y * Wp[(size_t)(k4*4+1)*256];
    acc += av.z * Wp[(size_t)(k4*4+2)*256];
    acc += av.w * Wp[(size_t)(k4*4+3)*256];
  }
  dst[(size_t)row*D_ + o] = snl[(size_t)row*D_ + o] + acc + b2[o];
}

extern "C" void kernel_launch(void* const* d_in, const int* in_sizes, int n_in,
                              void* d_out, int out_size, void* d_ws, size_t ws_size,
                              hipStream_t stream)
{
  const float* x       = (const float*)d_in[0];
  const float* noise   = (const float*)d_in[1];
  const float* mu      = (const float*)d_in[2];
  const float* lsig    = (const float*)d_in[3];
  const float* ln_in_g = (const float*)d_in[4];
  const float* ln_in_b = (const float*)d_in[5];
  const float* ln_s_g  = (const float*)d_in[6];
  const float* ln_s_b  = (const float*)d_in[7];
  const float* ln_ff_g = (const float*)d_in[8];
  const float* ln_ff_b = (const float*)d_in[9];
  const float* Wq  = (const float*)d_in[10]; const float* bq  = (const float*)d_in[11];
  const float* Wk  = (const float*)d_in[12]; const float* bk  = (const float*)d_in[13];
  const float* Wv  = (const float*)d_in[14]; const float* bv  = (const float*)d_in[15];
  const float* Wc  = (const float*)d_in[16]; const float* bc  = (const float*)d_in[17];
  const float* wih = (const float*)d_in[18]; const float* whh = (const float*)d_in[19];
  const float* bih = (const float*)d_in[20]; const float* bhh = (const float*)d_in[21];
  const float* W1  = (const float*)d_in[22]; const float* b1  = (const float*)d_in[23];
  const float* W2  = (const float*)d_in[24]; const float* b2  = (const float*)d_in[25];

  char* ws = (char*)d_ws;
  unsigned short* xn  = (unsigned short*)(ws + 0);
  unsigned short* xnT = (unsigned short*)(ws + 67108864);
  float* slots = (float*)(ws + 134217728);
  unsigned short* qp = (unsigned short*)(ws + 134742016);
  float* qb   = (float*)(ws + 136839168);
  float* mP   = (float*)(ws + 136855552);
  float* lP   = (float*)(ws + 136986624);
  float* axP  = (float*)(ws + 137117696);
  float* upd  = (float*)(ws + 170672128);
  float* WqT  = (float*)(ws + 171720704);
  float* WvT  = (float*)(ws + 172244992);
  float* WcT  = (float*)(ws + 172769280);
  float* wihT = (float*)(ws + 173293568);
  float* whhT = (float*)(ws + 174080000);
  float* W1T  = (float*)(ws + 174866432);
  float* W2T  = (float*)(ws + 175915008);
  // overlays inside axP region (dead at their use times):
  float* updc = (float*)(ws + 137117696);
  float* snl  = (float*)(ws + 137641984);
  float* h1   = (float*)(ws + 138166272);
  float* ql   = (float*)(ws + 141000704);   // consumed by preB before flash writes axP

  if (ws_size < (size_t)176963584ull){
    k_badws<<<512, 256, 0, stream>>>((float*)d_out);
    return;
  }

  k_init_slots<<<512, 256, 0, stream>>>(noise, mu, lsig, slots);
  k_ln_x<<<2048, 256, 0, stream>>>(x, ln_in_g, ln_in_b, xn, xnT);
  k_tr_all<<<1280, dim3(32, 8), 0, stream>>>(Wq, Wv, Wc, wih, whh, W1, W2,
                                             WqT, WvT, WcT, wihT, whhT, W1T, W2T);

  for (int it = 0; it < 3; ++it){
    k_preA<<<dim3(128, 8), 256, 0, stream>>>(slots, ln_s_g, ln_s_b, WqT, bq, ql);
    k_preB<<<dim3(256, 4), 256, 0, stream>>>(ql, Wk, bk, qp, qb);
    k_flash<<<dim3(CH_, B_), 512, 0, stream>>>(xn, xnT, qp, qb, mP, lP, axP);
    k_combine<<<1024, 256, 0, stream>>>(mP, lP, axP, WvT, bv, upd);
    k_sA<<<dim3(128, 4),  256, 0, stream>>>(upd, WcT, bc, updc);
    k_sB<<<dim3(128, 4),  256, 0, stream>>>(updc, slots, wihT, whhT, bih, bhh, snl);
    k_sC<<<dim3(128, 16), 256, 0, stream>>>(snl, ln_ff_g, ln_ff_b, W1T, b1, h1);
    k_sD<<<dim3(128, 4),  256, 0, stream>>>(h1, snl, W2T, b2, (it == 2) ? (float*)d_out : slots);
  }
}